// Round 1
// baseline (935.928 us; speedup 1.0000x reference)
//
#include <hip/hip_runtime.h>

#define N_NODES 50000
#define N_EDGES 800000
#define HIDDEN  128
#define OUT_F   10
#define N_GRAPHS 128
#define EPS 1e-5f

// ---------------------------------------------------------------------------
// 1) degree count: deg[dst]++ per edge
__global__ void deg_kernel(const int* __restrict__ dst, int* __restrict__ deg) {
    int e = blockIdx.x * blockDim.x + threadIdx.x;
    if (e < N_EDGES) atomicAdd(&deg[dst[e]], 1);
}

// 2) single-block exclusive scan of deg -> row_ptr; also inv_deg
__global__ void scan_kernel(const int* __restrict__ deg, int* __restrict__ row_ptr,
                            float* __restrict__ inv_deg) {
    __shared__ int s_part[1024];
    const int tid = threadIdx.x;
    const int C = (N_NODES + 1023) / 1024;  // 49
    int start = tid * C;
    int end = start + C; if (end > N_NODES) end = N_NODES; if (start > N_NODES) start = N_NODES;
    int sum = 0;
    for (int i = start; i < end; ++i) sum += deg[i];
    s_part[tid] = sum;
    __syncthreads();
    // Hillis-Steele inclusive scan
    for (int off = 1; off < 1024; off <<= 1) {
        int v = (tid >= off) ? s_part[tid - off] : 0;
        __syncthreads();
        s_part[tid] += v;
        __syncthreads();
    }
    int run = (tid == 0) ? 0 : s_part[tid - 1];
    for (int i = start; i < end; ++i) {
        row_ptr[i] = run;
        int d = deg[i];
        inv_deg[i] = (d > 0) ? (1.0f / (float)d) : 0.0f;
        run += d;
    }
    if (tid == 1023) row_ptr[N_NODES] = run;  // == N_EDGES
}

// 3) CSR fill: csr_src[row_ptr[dst] + slot] = src
__global__ void fill_kernel(const int* __restrict__ src, const int* __restrict__ dst,
                            const int* __restrict__ row_ptr, int* __restrict__ fill_cnt,
                            int* __restrict__ csr_src) {
    int e = blockIdx.x * blockDim.x + threadIdx.x;
    if (e < N_EDGES) {
        int d = dst[e];
        int p = row_ptr[d] + atomicAdd(&fill_cnt[d], 1);
        csr_src[p] = src[e];
    }
}

// 4) mean aggregation: one wave (64 lanes) per node, 2 floats per lane
__global__ void agg_kernel(const float* __restrict__ x, const int* __restrict__ row_ptr,
                           const int* __restrict__ csr_src, const float* __restrict__ inv_deg,
                           float* __restrict__ agg) {
    int gid = blockIdx.x * blockDim.x + threadIdx.x;
    int node = gid >> 6;
    int lane = threadIdx.x & 63;
    if (node >= N_NODES) return;
    int beg = row_ptr[node], end = row_ptr[node + 1];
    float ax = 0.f, ay = 0.f;
    const float2* xf = (const float2*)x;
    for (int e = beg; e < end; ++e) {
        int s = csr_src[e];
        float2 v = xf[(size_t)s * 64 + lane];
        ax += v.x; ay += v.y;
    }
    float w = inv_deg[node];
    float2 o; o.x = ax * w; o.y = ay * w;
    ((float2*)agg)[(size_t)node * 64 + lane] = o;
}

// 5) fused y = agg@W_rel + b_rel + x@W_root, LayerNorm(gamma,beta), ReLU
//    32-node tile in LDS, 256 threads, 4 nodes x 4 feats register tile.
#define BM 32
__global__ __launch_bounds__(256) void gemm_ln_kernel(
        const float* __restrict__ agg, const float* __restrict__ xin,
        float* __restrict__ xout,
        const float* __restrict__ Wrel, const float* __restrict__ brel,
        const float* __restrict__ Wroot, const float* __restrict__ gamma,
        const float* __restrict__ beta) {
    __shared__ float s_a[BM][HIDDEN];
    __shared__ float s_x[BM][HIDDEN];
    const int tid = threadIdx.x;
    const int base = blockIdx.x * BM;

    // cooperative load (float4): 32 rows x 32 float4 per array = 1024 f4 -> 4 iters
    for (int it = 0; it < 4; ++it) {
        int idx = it * 256 + tid;     // float4 index
        int row = idx >> 5;           // 0..31
        int col = idx & 31;           // float4 col
        int node = base + row;
        float4 av = {0.f,0.f,0.f,0.f}, xv = {0.f,0.f,0.f,0.f};
        if (node < N_NODES) {
            av = ((const float4*)agg)[(size_t)node * 32 + col];
            xv = ((const float4*)xin)[(size_t)node * 32 + col];
        }
        ((float4*)s_a[row])[col] = av;
        ((float4*)s_x[row])[col] = xv;
    }
    __syncthreads();

    const int tj = tid & 31;   // feature group: feats 4*tj..4*tj+3
    const int ti = tid >> 5;   // node subgroup: nodes 4*ti..4*ti+3

    float4 bb = ((const float4*)brel)[tj];
    float acc[4][4];
    #pragma unroll
    for (int i = 0; i < 4; ++i) { acc[i][0]=bb.x; acc[i][1]=bb.y; acc[i][2]=bb.z; acc[i][3]=bb.w; }

    for (int k = 0; k < HIDDEN; k += 4) {
        float4 wr0 = ((const float4*)(Wrel  + (size_t)(k+0) * HIDDEN))[tj];
        float4 wr1 = ((const float4*)(Wrel  + (size_t)(k+1) * HIDDEN))[tj];
        float4 wr2 = ((const float4*)(Wrel  + (size_t)(k+2) * HIDDEN))[tj];
        float4 wr3 = ((const float4*)(Wrel  + (size_t)(k+3) * HIDDEN))[tj];
        float4 wo0 = ((const float4*)(Wroot + (size_t)(k+0) * HIDDEN))[tj];
        float4 wo1 = ((const float4*)(Wroot + (size_t)(k+1) * HIDDEN))[tj];
        float4 wo2 = ((const float4*)(Wroot + (size_t)(k+2) * HIDDEN))[tj];
        float4 wo3 = ((const float4*)(Wroot + (size_t)(k+3) * HIDDEN))[tj];
        #pragma unroll
        for (int i = 0; i < 4; ++i) {
            int node = ti * 4 + i;
            float4 av = *(const float4*)&s_a[node][k];
            float4 xv = *(const float4*)&s_x[node][k];
            acc[i][0] += av.x*wr0.x + av.y*wr1.x + av.z*wr2.x + av.w*wr3.x
                       + xv.x*wo0.x + xv.y*wo1.x + xv.z*wo2.x + xv.w*wo3.x;
            acc[i][1] += av.x*wr0.y + av.y*wr1.y + av.z*wr2.y + av.w*wr3.y
                       + xv.x*wo0.y + xv.y*wo1.y + xv.z*wo2.y + xv.w*wo3.y;
            acc[i][2] += av.x*wr0.z + av.y*wr1.z + av.z*wr2.z + av.w*wr3.z
                       + xv.x*wo0.z + xv.y*wo1.z + xv.z*wo2.z + xv.w*wo3.z;
            acc[i][3] += av.x*wr0.w + av.y*wr1.w + av.z*wr2.w + av.w*wr3.w
                       + xv.x*wo0.w + xv.y*wo1.w + xv.z*wo2.w + xv.w*wo3.w;
        }
    }

    // LayerNorm over the 128 features of each node: features are spread across
    // the 32 tj-lanes (same half-wave since ti is the high 3 bits of tid).
    float4 gm = ((const float4*)gamma)[tj];
    float4 bt = ((const float4*)beta)[tj];
    #pragma unroll
    for (int i = 0; i < 4; ++i) {
        float s  = acc[i][0] + acc[i][1] + acc[i][2] + acc[i][3];
        float s2 = acc[i][0]*acc[i][0] + acc[i][1]*acc[i][1]
                 + acc[i][2]*acc[i][2] + acc[i][3]*acc[i][3];
        #pragma unroll
        for (int off = 16; off >= 1; off >>= 1) {  // stays within 32-lane half
            s  += __shfl_xor(s,  off, 64);
            s2 += __shfl_xor(s2, off, 64);
        }
        float mu  = s * (1.0f / HIDDEN);
        float var = s2 * (1.0f / HIDDEN) - mu * mu;
        float rs  = rsqrtf(var + EPS);
        int node = base + ti * 4 + i;
        if (node < N_NODES) {
            float4 o;
            o.x = fmaxf(gm.x * (acc[i][0] - mu) * rs + bt.x, 0.f);
            o.y = fmaxf(gm.y * (acc[i][1] - mu) * rs + bt.y, 0.f);
            o.z = fmaxf(gm.z * (acc[i][2] - mu) * rs + bt.z, 0.f);
            o.w = fmaxf(gm.w * (acc[i][3] - mu) * rs + bt.w, 0.f);
            ((float4*)xout)[(size_t)node * 32 + tj] = o;
        }
    }
}

// 6) mean pool per graph via atomics
__global__ void pool_kernel(const float* __restrict__ x, const int* __restrict__ batch,
                            float* __restrict__ pooled, float* __restrict__ gcnt) {
    int idx = blockIdx.x * blockDim.x + threadIdx.x;  // node*128 + f
    if (idx >= N_NODES * HIDDEN) return;
    int n = idx >> 7, f = idx & 127;
    int g = batch[n];
    atomicAdd(&pooled[g * HIDDEN + f], x[idx]);
    if (f == 0) atomicAdd(&gcnt[g], 1.0f);
}

// 7) head: out[g][o] = (pooled[g]/max(cnt,1)) @ Wc + bc
__global__ void out_kernel(const float* __restrict__ pooled, const float* __restrict__ gcnt,
                           const float* __restrict__ Wc, const float* __restrict__ bc,
                           float* __restrict__ out) {
    int idx = blockIdx.x * blockDim.x + threadIdx.x;
    if (idx >= N_GRAPHS * OUT_F) return;
    int g = idx / OUT_F, o = idx % OUT_F;
    float inv = 1.0f / fmaxf(gcnt[g], 1.0f);
    float s = 0.f;
    for (int f = 0; f < HIDDEN; ++f)
        s += pooled[g * HIDDEN + f] * Wc[f * OUT_F + o];
    out[idx] = s * inv + bc[o];
}

// ---------------------------------------------------------------------------
static inline size_t align256(size_t v) { return (v + 255) & ~(size_t)255; }

extern "C" void kernel_launch(void* const* d_in, const int* in_sizes, int n_in,
                              void* d_out, int out_size, void* d_ws, size_t ws_size,
                              hipStream_t stream) {
    const float* x      = (const float*)d_in[0];
    const int*   eidx   = (const int*)d_in[1];   // [2, E]: row0 src, row1 dst
    const int*   batch  = (const int*)d_in[2];
    const float* W_rel  = (const float*)d_in[3]; // [2,128,128]
    const float* b_rel  = (const float*)d_in[4]; // [2,128]
    const float* W_root = (const float*)d_in[5]; // [2,128,128]
    const float* gamma  = (const float*)d_in[6]; // [2,128]
    const float* beta   = (const float*)d_in[7]; // [2,128]
    const float* Wc     = (const float*)d_in[8]; // [128,10]
    const float* bc     = (const float*)d_in[9]; // [10]
    float* out = (float*)d_out;

    const int* src = eidx;
    const int* dst = eidx + N_EDGES;

    // workspace carve-up
    char* ws = (char*)d_ws;
    size_t off = 0;
    int*   deg      = (int*)(ws + off);  off = align256(off + sizeof(int) * N_NODES);
    int*   row_ptr  = (int*)(ws + off);  off = align256(off + sizeof(int) * (N_NODES + 1));
    int*   fill_cnt = (int*)(ws + off);  off = align256(off + sizeof(int) * N_NODES);
    int*   csr_src  = (int*)(ws + off);  off = align256(off + sizeof(int) * N_EDGES);
    float* inv_deg  = (float*)(ws + off); off = align256(off + sizeof(float) * N_NODES);
    float* x_buf    = (float*)(ws + off); off = align256(off + sizeof(float) * (size_t)N_NODES * HIDDEN);
    float* agg      = (float*)(ws + off); off = align256(off + sizeof(float) * (size_t)N_NODES * HIDDEN);
    float* pooled   = (float*)(ws + off); off = align256(off + sizeof(float) * N_GRAPHS * HIDDEN);
    float* gcnt     = (float*)(ws + off); off = align256(off + sizeof(float) * N_GRAPHS);

    // zero-init (ws is poisoned 0xAA before every launch)
    hipMemsetAsync(deg,      0, sizeof(int) * N_NODES, stream);
    hipMemsetAsync(fill_cnt, 0, sizeof(int) * N_NODES, stream);
    hipMemsetAsync(pooled,   0, sizeof(float) * N_GRAPHS * HIDDEN, stream);
    hipMemsetAsync(gcnt,     0, sizeof(float) * N_GRAPHS, stream);

    // CSR build (once; reused by both layers)
    deg_kernel <<<N_EDGES / 256, 256, 0, stream>>>(dst, deg);
    scan_kernel<<<1, 1024, 0, stream>>>(deg, row_ptr, inv_deg);
    fill_kernel<<<N_EDGES / 256, 256, 0, stream>>>(src, dst, row_ptr, fill_cnt, csr_src);

    const int agg_blocks  = (N_NODES * 64) / 256;          // 12500
    const int gemm_blocks = (N_NODES + BM - 1) / BM;       // 1563

    // layer 0
    agg_kernel<<<agg_blocks, 256, 0, stream>>>(x, row_ptr, csr_src, inv_deg, agg);
    gemm_ln_kernel<<<gemm_blocks, 256, 0, stream>>>(
        agg, x, x_buf, W_rel, b_rel, W_root, gamma, beta);
    // layer 1 (in-place on x_buf is safe: each block reads its rows into LDS
    // before writing them back, and no other block touches those rows)
    agg_kernel<<<agg_blocks, 256, 0, stream>>>(x_buf, row_ptr, csr_src, inv_deg, agg);
    gemm_ln_kernel<<<gemm_blocks, 256, 0, stream>>>(
        agg, x_buf, x_buf, W_rel + HIDDEN * HIDDEN, b_rel + HIDDEN,
        W_root + HIDDEN * HIDDEN, gamma + HIDDEN, beta + HIDDEN);

    // pooling + head
    pool_kernel<<<(N_NODES * HIDDEN) / 256, 256, 0, stream>>>(x_buf, batch, pooled, gcnt);
    out_kernel<<<(N_GRAPHS * OUT_F + 255) / 256, 256, 0, stream>>>(pooled, gcnt, Wc, bc, out);
}

// Round 2
// 650.424 us; speedup vs baseline: 1.4390x; 1.4390x over previous
//
#include <hip/hip_runtime.h>

#define N_NODES 50000
#define N_EDGES 800000
#define HIDDEN  128
#define OUT_F   10
#define N_GRAPHS 128
#define EPS 1e-5f

// ---------------------------------------------------------------------------
// 1) degree count: deg[dst]++ per edge
__global__ void deg_kernel(const int* __restrict__ dst, int* __restrict__ deg) {
    int e = blockIdx.x * blockDim.x + threadIdx.x;
    if (e < N_EDGES) atomicAdd(&deg[dst[e]], 1);
}

// 2) single-block exclusive scan of deg -> row_ptr; also inv_deg
__global__ void scan_kernel(const int* __restrict__ deg, int* __restrict__ row_ptr,
                            float* __restrict__ inv_deg) {
    __shared__ int s_part[1024];
    const int tid = threadIdx.x;
    const int C = (N_NODES + 1023) / 1024;  // 49
    int start = tid * C;
    int end = start + C; if (end > N_NODES) end = N_NODES; if (start > N_NODES) start = N_NODES;
    int sum = 0;
    for (int i = start; i < end; ++i) sum += deg[i];
    s_part[tid] = sum;
    __syncthreads();
    // Hillis-Steele inclusive scan
    for (int off = 1; off < 1024; off <<= 1) {
        int v = (tid >= off) ? s_part[tid - off] : 0;
        __syncthreads();
        s_part[tid] += v;
        __syncthreads();
    }
    int run = (tid == 0) ? 0 : s_part[tid - 1];
    for (int i = start; i < end; ++i) {
        row_ptr[i] = run;
        int d = deg[i];
        inv_deg[i] = (d > 0) ? (1.0f / (float)d) : 0.0f;
        run += d;
    }
    if (tid == 1023) row_ptr[N_NODES] = run;  // == N_EDGES
}

// 3) CSR fill: csr_src[row_ptr[dst] + slot] = src
__global__ void fill_kernel(const int* __restrict__ src, const int* __restrict__ dst,
                            const int* __restrict__ row_ptr, int* __restrict__ fill_cnt,
                            int* __restrict__ csr_src) {
    int e = blockIdx.x * blockDim.x + threadIdx.x;
    if (e < N_EDGES) {
        int d = dst[e];
        int p = row_ptr[d] + atomicAdd(&fill_cnt[d], 1);
        csr_src[p] = src[e];
    }
}

// 4) mean aggregation: one wave (64 lanes) per node, 2 floats per lane
__global__ void agg_kernel(const float* __restrict__ x, const int* __restrict__ row_ptr,
                           const int* __restrict__ csr_src, const float* __restrict__ inv_deg,
                           float* __restrict__ agg) {
    int gid = blockIdx.x * blockDim.x + threadIdx.x;
    int node = gid >> 6;
    int lane = threadIdx.x & 63;
    if (node >= N_NODES) return;
    int beg = row_ptr[node], end = row_ptr[node + 1];
    float ax = 0.f, ay = 0.f;
    const float2* xf = (const float2*)x;
    for (int e = beg; e < end; ++e) {
        int s = csr_src[e];
        float2 v = xf[(size_t)s * 64 + lane];
        ax += v.x; ay += v.y;
    }
    float w = inv_deg[node];
    float2 o; o.x = ax * w; o.y = ay * w;
    ((float2*)agg)[(size_t)node * 64 + lane] = o;
}

// 5) fused y = agg@W_rel + b_rel + x@W_root, LayerNorm(gamma,beta), ReLU
//    32-node tile in LDS, 256 threads, 4 nodes x 4 feats register tile.
#define BM 32
__global__ __launch_bounds__(256) void gemm_ln_kernel(
        const float* __restrict__ agg, const float* __restrict__ xin,
        float* __restrict__ xout,
        const float* __restrict__ Wrel, const float* __restrict__ brel,
        const float* __restrict__ Wroot, const float* __restrict__ gamma,
        const float* __restrict__ beta) {
    __shared__ float s_a[BM][HIDDEN];
    __shared__ float s_x[BM][HIDDEN];
    const int tid = threadIdx.x;
    const int base = blockIdx.x * BM;

    // cooperative load (float4): 32 rows x 32 float4 per array = 1024 f4 -> 4 iters
    for (int it = 0; it < 4; ++it) {
        int idx = it * 256 + tid;     // float4 index
        int row = idx >> 5;           // 0..31
        int col = idx & 31;           // float4 col
        int node = base + row;
        float4 av = {0.f,0.f,0.f,0.f}, xv = {0.f,0.f,0.f,0.f};
        if (node < N_NODES) {
            av = ((const float4*)agg)[(size_t)node * 32 + col];
            xv = ((const float4*)xin)[(size_t)node * 32 + col];
        }
        ((float4*)s_a[row])[col] = av;
        ((float4*)s_x[row])[col] = xv;
    }
    __syncthreads();

    const int tj = tid & 31;   // feature group: feats 4*tj..4*tj+3
    const int ti = tid >> 5;   // node subgroup: nodes 4*ti..4*ti+3

    float4 bb = ((const float4*)brel)[tj];
    float acc[4][4];
    #pragma unroll
    for (int i = 0; i < 4; ++i) { acc[i][0]=bb.x; acc[i][1]=bb.y; acc[i][2]=bb.z; acc[i][3]=bb.w; }

    for (int k = 0; k < HIDDEN; k += 4) {
        float4 wr0 = ((const float4*)(Wrel  + (size_t)(k+0) * HIDDEN))[tj];
        float4 wr1 = ((const float4*)(Wrel  + (size_t)(k+1) * HIDDEN))[tj];
        float4 wr2 = ((const float4*)(Wrel  + (size_t)(k+2) * HIDDEN))[tj];
        float4 wr3 = ((const float4*)(Wrel  + (size_t)(k+3) * HIDDEN))[tj];
        float4 wo0 = ((const float4*)(Wroot + (size_t)(k+0) * HIDDEN))[tj];
        float4 wo1 = ((const float4*)(Wroot + (size_t)(k+1) * HIDDEN))[tj];
        float4 wo2 = ((const float4*)(Wroot + (size_t)(k+2) * HIDDEN))[tj];
        float4 wo3 = ((const float4*)(Wroot + (size_t)(k+3) * HIDDEN))[tj];
        #pragma unroll
        for (int i = 0; i < 4; ++i) {
            int node = ti * 4 + i;
            float4 av = *(const float4*)&s_a[node][k];
            float4 xv = *(const float4*)&s_x[node][k];
            acc[i][0] += av.x*wr0.x + av.y*wr1.x + av.z*wr2.x + av.w*wr3.x
                       + xv.x*wo0.x + xv.y*wo1.x + xv.z*wo2.x + xv.w*wo3.x;
            acc[i][1] += av.x*wr0.y + av.y*wr1.y + av.z*wr2.y + av.w*wr3.y
                       + xv.x*wo0.y + xv.y*wo1.y + xv.z*wo2.y + xv.w*wo3.y;
            acc[i][2] += av.x*wr0.z + av.y*wr1.z + av.z*wr2.z + av.w*wr3.z
                       + xv.x*wo0.z + xv.y*wo1.z + xv.z*wo2.z + xv.w*wo3.z;
            acc[i][3] += av.x*wr0.w + av.y*wr1.w + av.z*wr2.w + av.w*wr3.w
                       + xv.x*wo0.w + xv.y*wo1.w + xv.z*wo2.w + xv.w*wo3.w;
        }
    }

    // LayerNorm over the 128 features of each node: features are spread across
    // the 32 tj-lanes (same half-wave since ti is the high 3 bits of tid).
    float4 gm = ((const float4*)gamma)[tj];
    float4 bt = ((const float4*)beta)[tj];
    #pragma unroll
    for (int i = 0; i < 4; ++i) {
        float s  = acc[i][0] + acc[i][1] + acc[i][2] + acc[i][3];
        float s2 = acc[i][0]*acc[i][0] + acc[i][1]*acc[i][1]
                 + acc[i][2]*acc[i][2] + acc[i][3]*acc[i][3];
        #pragma unroll
        for (int off = 16; off >= 1; off >>= 1) {  // stays within 32-lane half
            s  += __shfl_xor(s,  off, 64);
            s2 += __shfl_xor(s2, off, 64);
        }
        float mu  = s * (1.0f / HIDDEN);
        float var = s2 * (1.0f / HIDDEN) - mu * mu;
        float rs  = rsqrtf(var + EPS);
        int node = base + ti * 4 + i;
        if (node < N_NODES) {
            float4 o;
            o.x = fmaxf(gm.x * (acc[i][0] - mu) * rs + bt.x, 0.f);
            o.y = fmaxf(gm.y * (acc[i][1] - mu) * rs + bt.y, 0.f);
            o.z = fmaxf(gm.z * (acc[i][2] - mu) * rs + bt.z, 0.f);
            o.w = fmaxf(gm.w * (acc[i][3] - mu) * rs + bt.w, 0.f);
            ((float4*)xout)[(size_t)node * 32 + tj] = o;
        }
    }
}

// 6) segmented mean-pool exploiting SORTED batch: each wave owns a contiguous
//    node range, keeps a running per-lane float2 sum, flushes on graph change.
//    ~2 flushes/wave -> ~260K atomics total (vs 6.4M naive).
#define POOL_WAVES 1024
#define POOL_CHUNK ((N_NODES + POOL_WAVES - 1) / POOL_WAVES)  // 49
__global__ void pool_kernel(const float* __restrict__ x, const int* __restrict__ batch,
                            float* __restrict__ pooled) {
    int wave = blockIdx.x * (blockDim.x >> 6) + (threadIdx.x >> 6);
    int lane = threadIdx.x & 63;
    int n0 = wave * POOL_CHUNK;
    int n1 = n0 + POOL_CHUNK; if (n1 > N_NODES) n1 = N_NODES;
    if (n0 >= N_NODES) return;
    const float2* xf = (const float2*)x;
    int cur_g = batch[n0];
    float sx = 0.f, sy = 0.f;
    for (int n = n0; n < n1; ++n) {
        int g = batch[n];  // wave-uniform scalar broadcast
        if (g != cur_g) {
            atomicAdd(&pooled[cur_g * HIDDEN + lane * 2 + 0], sx);
            atomicAdd(&pooled[cur_g * HIDDEN + lane * 2 + 1], sy);
            sx = 0.f; sy = 0.f; cur_g = g;
        }
        float2 v = xf[(size_t)n * 64 + lane];
        sx += v.x; sy += v.y;
    }
    atomicAdd(&pooled[cur_g * HIDDEN + lane * 2 + 0], sx);
    atomicAdd(&pooled[cur_g * HIDDEN + lane * 2 + 1], sy);
}

// 6b) per-graph node counts via binary search on the sorted batch array
__global__ void cnt_kernel(const int* __restrict__ batch, float* __restrict__ gcnt) {
    int g = threadIdx.x;
    if (g >= N_GRAPHS) return;
    // lower_bound(g) and lower_bound(g+1)
    int lo = 0, hi = N_NODES;
    while (lo < hi) { int m = (lo + hi) >> 1; if (batch[m] < g) lo = m + 1; else hi = m; }
    int b0 = lo;
    lo = 0; hi = N_NODES;
    while (lo < hi) { int m = (lo + hi) >> 1; if (batch[m] < g + 1) lo = m + 1; else hi = m; }
    gcnt[g] = (float)(lo - b0);
}

// 7) head: out[g][o] = (pooled[g]/max(cnt,1)) @ Wc + bc
__global__ void out_kernel(const float* __restrict__ pooled, const float* __restrict__ gcnt,
                           const float* __restrict__ Wc, const float* __restrict__ bc,
                           float* __restrict__ out) {
    int idx = blockIdx.x * blockDim.x + threadIdx.x;
    if (idx >= N_GRAPHS * OUT_F) return;
    int g = idx / OUT_F, o = idx % OUT_F;
    float inv = 1.0f / fmaxf(gcnt[g], 1.0f);
    float s = 0.f;
    for (int f = 0; f < HIDDEN; ++f)
        s += pooled[g * HIDDEN + f] * Wc[f * OUT_F + o];
    out[idx] = s * inv + bc[o];
}

// ---------------------------------------------------------------------------
static inline size_t align256(size_t v) { return (v + 255) & ~(size_t)255; }

extern "C" void kernel_launch(void* const* d_in, const int* in_sizes, int n_in,
                              void* d_out, int out_size, void* d_ws, size_t ws_size,
                              hipStream_t stream) {
    const float* x      = (const float*)d_in[0];
    const int*   eidx   = (const int*)d_in[1];   // [2, E]: row0 src, row1 dst
    const int*   batch  = (const int*)d_in[2];
    const float* W_rel  = (const float*)d_in[3]; // [2,128,128]
    const float* b_rel  = (const float*)d_in[4]; // [2,128]
    const float* W_root = (const float*)d_in[5]; // [2,128,128]
    const float* gamma  = (const float*)d_in[6]; // [2,128]
    const float* beta   = (const float*)d_in[7]; // [2,128]
    const float* Wc     = (const float*)d_in[8]; // [128,10]
    const float* bc     = (const float*)d_in[9]; // [10]
    float* out = (float*)d_out;

    const int* src = eidx;
    const int* dst = eidx + N_EDGES;

    // workspace carve-up
    char* ws = (char*)d_ws;
    size_t off = 0;
    int*   deg      = (int*)(ws + off);  off = align256(off + sizeof(int) * N_NODES);
    int*   row_ptr  = (int*)(ws + off);  off = align256(off + sizeof(int) * (N_NODES + 1));
    int*   fill_cnt = (int*)(ws + off);  off = align256(off + sizeof(int) * N_NODES);
    int*   csr_src  = (int*)(ws + off);  off = align256(off + sizeof(int) * N_EDGES);
    float* inv_deg  = (float*)(ws + off); off = align256(off + sizeof(float) * N_NODES);
    float* x_buf    = (float*)(ws + off); off = align256(off + sizeof(float) * (size_t)N_NODES * HIDDEN);
    float* agg      = (float*)(ws + off); off = align256(off + sizeof(float) * (size_t)N_NODES * HIDDEN);
    float* pooled   = (float*)(ws + off); off = align256(off + sizeof(float) * N_GRAPHS * HIDDEN);
    float* gcnt     = (float*)(ws + off); off = align256(off + sizeof(float) * N_GRAPHS);

    // zero-init (ws is poisoned 0xAA before every launch)
    hipMemsetAsync(deg,      0, sizeof(int) * N_NODES, stream);
    hipMemsetAsync(fill_cnt, 0, sizeof(int) * N_NODES, stream);
    hipMemsetAsync(pooled,   0, sizeof(float) * N_GRAPHS * HIDDEN, stream);

    // CSR build (once; reused by both layers)
    deg_kernel <<<N_EDGES / 256, 256, 0, stream>>>(dst, deg);
    scan_kernel<<<1, 1024, 0, stream>>>(deg, row_ptr, inv_deg);
    fill_kernel<<<N_EDGES / 256, 256, 0, stream>>>(src, dst, row_ptr, fill_cnt, csr_src);

    const int agg_blocks  = (N_NODES * 64) / 256;          // 12500
    const int gemm_blocks = (N_NODES + BM - 1) / BM;       // 1563

    // layer 0
    agg_kernel<<<agg_blocks, 256, 0, stream>>>(x, row_ptr, csr_src, inv_deg, agg);
    gemm_ln_kernel<<<gemm_blocks, 256, 0, stream>>>(
        agg, x, x_buf, W_rel, b_rel, W_root, gamma, beta);
    // layer 1 (in-place on x_buf is safe: each block reads its rows into LDS
    // before writing them back, and no other block touches those rows)
    agg_kernel<<<agg_blocks, 256, 0, stream>>>(x_buf, row_ptr, csr_src, inv_deg, agg);
    gemm_ln_kernel<<<gemm_blocks, 256, 0, stream>>>(
        agg, x_buf, x_buf, W_rel + HIDDEN * HIDDEN, b_rel + HIDDEN,
        W_root + HIDDEN * HIDDEN, gamma + HIDDEN, beta + HIDDEN);

    // pooling + head (batch is sorted -> segmented pool, few atomics)
    pool_kernel<<<POOL_WAVES / 4, 256, 0, stream>>>(x_buf, batch, pooled);
    cnt_kernel<<<1, 128, 0, stream>>>(batch, gcnt);
    out_kernel<<<(N_GRAPHS * OUT_F + 255) / 256, 256, 0, stream>>>(pooled, gcnt, Wc, bc, out);
}

// Round 3
// 551.476 us; speedup vs baseline: 1.6971x; 1.1794x over previous
//
#include <hip/hip_runtime.h>

#define N_NODES 50000
#define N_EDGES 800000
#define HIDDEN  128
#define OUT_F   10
#define N_GRAPHS 128
#define EPS 1e-5f

#define SCAN_BLOCKS ((N_NODES + 255) / 256)   // 196

// ---------------------------------------------------------------------------
// 1) degree count: deg[dst]++ per edge
__global__ void deg_kernel(const int* __restrict__ dst, int* __restrict__ deg) {
    int e = blockIdx.x * blockDim.x + threadIdx.x;
    if (e < N_EDGES) atomicAdd(&deg[dst[e]], 1);
}

// 2a) per-block sums of deg (coalesced, one elem/thread)
__global__ void scan1_kernel(const int* __restrict__ deg, int* __restrict__ partials) {
    int i = blockIdx.x * 256 + threadIdx.x;
    int v = (i < N_NODES) ? deg[i] : 0;
    #pragma unroll
    for (int off = 1; off < 64; off <<= 1) v += __shfl_xor(v, off, 64);
    __shared__ int s[4];
    if ((threadIdx.x & 63) == 0) s[threadIdx.x >> 6] = v;
    __syncthreads();
    if (threadIdx.x == 0) partials[blockIdx.x] = s[0] + s[1] + s[2] + s[3];
}

// 2b) exclusive scan of the 196 block partials (single tiny block)
__global__ void scan2_kernel(const int* __restrict__ partials, int* __restrict__ block_off) {
    __shared__ int s[256];
    int tid = threadIdx.x;
    int v = (tid < SCAN_BLOCKS) ? partials[tid] : 0;
    s[tid] = v;
    __syncthreads();
    #pragma unroll
    for (int off = 1; off < 256; off <<= 1) {
        int t = (tid >= off) ? s[tid - off] : 0;
        __syncthreads();
        s[tid] += t;
        __syncthreads();
    }
    if (tid < SCAN_BLOCKS) block_off[tid] = s[tid] - v;  // exclusive
}

// 2c) block-local inclusive shuffle-scan + offset -> row_ptr, inv_deg
__global__ void scan3_kernel(const int* __restrict__ deg, const int* __restrict__ block_off,
                             int* __restrict__ row_ptr, float* __restrict__ inv_deg) {
    int i = blockIdx.x * 256 + threadIdx.x;
    int d = (i < N_NODES) ? deg[i] : 0;
    int lane = threadIdx.x & 63;
    int v = d;
    #pragma unroll
    for (int off = 1; off < 64; off <<= 1) {
        int t = __shfl_up(v, off, 64);
        if (lane >= off) v += t;
    }
    __shared__ int wsum[4];
    if (lane == 63) wsum[threadIdx.x >> 6] = v;
    __syncthreads();
    int w = threadIdx.x >> 6;
    int woff = 0;
    #pragma unroll
    for (int j = 0; j < 4; ++j) if (j < w) woff += wsum[j];
    int excl = block_off[blockIdx.x] + woff + v - d;
    if (i < N_NODES) {
        row_ptr[i] = excl;
        inv_deg[i] = (d > 0) ? (1.0f / (float)d) : 0.0f;
    }
    if (blockIdx.x == 0 && threadIdx.x == 0) row_ptr[N_NODES] = N_EDGES;
}

// 3) CSR fill: csr_src[row_ptr[dst] + slot] = src
__global__ void fill_kernel(const int* __restrict__ src, const int* __restrict__ dst,
                            const int* __restrict__ row_ptr, int* __restrict__ fill_cnt,
                            int* __restrict__ csr_src) {
    int e = blockIdx.x * blockDim.x + threadIdx.x;
    if (e < N_EDGES) {
        int d = dst[e];
        int p = row_ptr[d] + atomicAdd(&fill_cnt[d], 1);
        csr_src[p] = src[e];
    }
}

// 4) mean aggregation: one wave (64 lanes) per node, 2 floats per lane
__global__ void agg_kernel(const float* __restrict__ x, const int* __restrict__ row_ptr,
                           const int* __restrict__ csr_src, const float* __restrict__ inv_deg,
                           float* __restrict__ agg) {
    int gid = blockIdx.x * blockDim.x + threadIdx.x;
    int node = gid >> 6;
    int lane = threadIdx.x & 63;
    if (node >= N_NODES) return;
    int beg = row_ptr[node], end = row_ptr[node + 1];
    float ax = 0.f, ay = 0.f;
    const float2* xf = (const float2*)x;
    for (int e = beg; e < end; ++e) {
        int s = csr_src[e];
        float2 v = xf[(size_t)s * 64 + lane];
        ax += v.x; ay += v.y;
    }
    float w = inv_deg[node];
    float2 o; o.x = ax * w; o.y = ay * w;
    ((float2*)agg)[(size_t)node * 64 + lane] = o;
}

// 5) fused y = agg@W_rel + b_rel + x@W_root, LayerNorm(gamma,beta), ReLU
#define BM 32
__global__ __launch_bounds__(256) void gemm_ln_kernel(
        const float* __restrict__ agg, const float* __restrict__ xin,
        float* __restrict__ xout,
        const float* __restrict__ Wrel, const float* __restrict__ brel,
        const float* __restrict__ Wroot, const float* __restrict__ gamma,
        const float* __restrict__ beta) {
    __shared__ float s_a[BM][HIDDEN];
    __shared__ float s_x[BM][HIDDEN];
    const int tid = threadIdx.x;
    const int base = blockIdx.x * BM;

    for (int it = 0; it < 4; ++it) {
        int idx = it * 256 + tid;
        int row = idx >> 5;
        int col = idx & 31;
        int node = base + row;
        float4 av = {0.f,0.f,0.f,0.f}, xv = {0.f,0.f,0.f,0.f};
        if (node < N_NODES) {
            av = ((const float4*)agg)[(size_t)node * 32 + col];
            xv = ((const float4*)xin)[(size_t)node * 32 + col];
        }
        ((float4*)s_a[row])[col] = av;
        ((float4*)s_x[row])[col] = xv;
    }
    __syncthreads();

    const int tj = tid & 31;
    const int ti = tid >> 5;

    float4 bb = ((const float4*)brel)[tj];
    float acc[4][4];
    #pragma unroll
    for (int i = 0; i < 4; ++i) { acc[i][0]=bb.x; acc[i][1]=bb.y; acc[i][2]=bb.z; acc[i][3]=bb.w; }

    for (int k = 0; k < HIDDEN; k += 4) {
        float4 wr0 = ((const float4*)(Wrel  + (size_t)(k+0) * HIDDEN))[tj];
        float4 wr1 = ((const float4*)(Wrel  + (size_t)(k+1) * HIDDEN))[tj];
        float4 wr2 = ((const float4*)(Wrel  + (size_t)(k+2) * HIDDEN))[tj];
        float4 wr3 = ((const float4*)(Wrel  + (size_t)(k+3) * HIDDEN))[tj];
        float4 wo0 = ((const float4*)(Wroot + (size_t)(k+0) * HIDDEN))[tj];
        float4 wo1 = ((const float4*)(Wroot + (size_t)(k+1) * HIDDEN))[tj];
        float4 wo2 = ((const float4*)(Wroot + (size_t)(k+2) * HIDDEN))[tj];
        float4 wo3 = ((const float4*)(Wroot + (size_t)(k+3) * HIDDEN))[tj];
        #pragma unroll
        for (int i = 0; i < 4; ++i) {
            int node = ti * 4 + i;
            float4 av = *(const float4*)&s_a[node][k];
            float4 xv = *(const float4*)&s_x[node][k];
            acc[i][0] += av.x*wr0.x + av.y*wr1.x + av.z*wr2.x + av.w*wr3.x
                       + xv.x*wo0.x + xv.y*wo1.x + xv.z*wo2.x + xv.w*wo3.x;
            acc[i][1] += av.x*wr0.y + av.y*wr1.y + av.z*wr2.y + av.w*wr3.y
                       + xv.x*wo0.y + xv.y*wo1.y + xv.z*wo2.y + xv.w*wo3.y;
            acc[i][2] += av.x*wr0.z + av.y*wr1.z + av.z*wr2.z + av.w*wr3.z
                       + xv.x*wo0.z + xv.y*wo1.z + xv.z*wo2.z + xv.w*wo3.z;
            acc[i][3] += av.x*wr0.w + av.y*wr1.w + av.z*wr2.w + av.w*wr3.w
                       + xv.x*wo0.w + xv.y*wo1.w + xv.z*wo2.w + xv.w*wo3.w;
        }
    }

    float4 gm = ((const float4*)gamma)[tj];
    float4 bt = ((const float4*)beta)[tj];
    #pragma unroll
    for (int i = 0; i < 4; ++i) {
        float s  = acc[i][0] + acc[i][1] + acc[i][2] + acc[i][3];
        float s2 = acc[i][0]*acc[i][0] + acc[i][1]*acc[i][1]
                 + acc[i][2]*acc[i][2] + acc[i][3]*acc[i][3];
        #pragma unroll
        for (int off = 16; off >= 1; off >>= 1) {
            s  += __shfl_xor(s,  off, 64);
            s2 += __shfl_xor(s2, off, 64);
        }
        float mu  = s * (1.0f / HIDDEN);
        float var = s2 * (1.0f / HIDDEN) - mu * mu;
        float rs  = rsqrtf(var + EPS);
        int node = base + ti * 4 + i;
        if (node < N_NODES) {
            float4 o;
            o.x = fmaxf(gm.x * (acc[i][0] - mu) * rs + bt.x, 0.f);
            o.y = fmaxf(gm.y * (acc[i][1] - mu) * rs + bt.y, 0.f);
            o.z = fmaxf(gm.z * (acc[i][2] - mu) * rs + bt.z, 0.f);
            o.w = fmaxf(gm.w * (acc[i][3] - mu) * rs + bt.w, 0.f);
            ((float4*)xout)[(size_t)node * 32 + tj] = o;
        }
    }
}

// 6) segmented mean-pool exploiting SORTED batch
#define POOL_WAVES 1024
#define POOL_CHUNK ((N_NODES + POOL_WAVES - 1) / POOL_WAVES)  // 49
__global__ void pool_kernel(const float* __restrict__ x, const int* __restrict__ batch,
                            float* __restrict__ pooled) {
    int wave = blockIdx.x * (blockDim.x >> 6) + (threadIdx.x >> 6);
    int lane = threadIdx.x & 63;
    int n0 = wave * POOL_CHUNK;
    int n1 = n0 + POOL_CHUNK; if (n1 > N_NODES) n1 = N_NODES;
    if (n0 >= N_NODES) return;
    const float2* xf = (const float2*)x;
    int cur_g = batch[n0];
    float sx = 0.f, sy = 0.f;
    for (int n = n0; n < n1; ++n) {
        int g = batch[n];
        if (g != cur_g) {
            atomicAdd(&pooled[cur_g * HIDDEN + lane * 2 + 0], sx);
            atomicAdd(&pooled[cur_g * HIDDEN + lane * 2 + 1], sy);
            sx = 0.f; sy = 0.f; cur_g = g;
        }
        float2 v = xf[(size_t)n * 64 + lane];
        sx += v.x; sy += v.y;
    }
    atomicAdd(&pooled[cur_g * HIDDEN + lane * 2 + 0], sx);
    atomicAdd(&pooled[cur_g * HIDDEN + lane * 2 + 1], sy);
}

// 6b) per-graph node counts via binary search on the sorted batch array
__global__ void cnt_kernel(const int* __restrict__ batch, float* __restrict__ gcnt) {
    int g = threadIdx.x;
    if (g >= N_GRAPHS) return;
    int lo = 0, hi = N_NODES;
    while (lo < hi) { int m = (lo + hi) >> 1; if (batch[m] < g) lo = m + 1; else hi = m; }
    int b0 = lo;
    lo = 0; hi = N_NODES;
    while (lo < hi) { int m = (lo + hi) >> 1; if (batch[m] < g + 1) lo = m + 1; else hi = m; }
    gcnt[g] = (float)(lo - b0);
}

// 7) head
__global__ void out_kernel(const float* __restrict__ pooled, const float* __restrict__ gcnt,
                           const float* __restrict__ Wc, const float* __restrict__ bc,
                           float* __restrict__ out) {
    int idx = blockIdx.x * blockDim.x + threadIdx.x;
    if (idx >= N_GRAPHS * OUT_F) return;
    int g = idx / OUT_F, o = idx % OUT_F;
    float inv = 1.0f / fmaxf(gcnt[g], 1.0f);
    float s = 0.f;
    for (int f = 0; f < HIDDEN; ++f)
        s += pooled[g * HIDDEN + f] * Wc[f * OUT_F + o];
    out[idx] = s * inv + bc[o];
}

// ---------------------------------------------------------------------------
static inline size_t align256(size_t v) { return (v + 255) & ~(size_t)255; }

extern "C" void kernel_launch(void* const* d_in, const int* in_sizes, int n_in,
                              void* d_out, int out_size, void* d_ws, size_t ws_size,
                              hipStream_t stream) {
    const float* x      = (const float*)d_in[0];
    const int*   eidx   = (const int*)d_in[1];
    const int*   batch  = (const int*)d_in[2];
    const float* W_rel  = (const float*)d_in[3];
    const float* b_rel  = (const float*)d_in[4];
    const float* W_root = (const float*)d_in[5];
    const float* gamma  = (const float*)d_in[6];
    const float* beta   = (const float*)d_in[7];
    const float* Wc     = (const float*)d_in[8];
    const float* bc     = (const float*)d_in[9];
    float* out = (float*)d_out;

    const int* src = eidx;
    const int* dst = eidx + N_EDGES;

    char* ws = (char*)d_ws;
    size_t off = 0;
    int*   deg      = (int*)(ws + off);  off = align256(off + sizeof(int) * N_NODES);
    int*   row_ptr  = (int*)(ws + off);  off = align256(off + sizeof(int) * (N_NODES + 1));
    int*   fill_cnt = (int*)(ws + off);  off = align256(off + sizeof(int) * N_NODES);
    int*   csr_src  = (int*)(ws + off);  off = align256(off + sizeof(int) * N_EDGES);
    float* inv_deg  = (float*)(ws + off); off = align256(off + sizeof(float) * N_NODES);
    int*   partials = (int*)(ws + off);  off = align256(off + sizeof(int) * SCAN_BLOCKS);
    int*   block_off= (int*)(ws + off);  off = align256(off + sizeof(int) * SCAN_BLOCKS);
    float* x_buf    = (float*)(ws + off); off = align256(off + sizeof(float) * (size_t)N_NODES * HIDDEN);
    float* agg      = (float*)(ws + off); off = align256(off + sizeof(float) * (size_t)N_NODES * HIDDEN);
    float* pooled   = (float*)(ws + off); off = align256(off + sizeof(float) * N_GRAPHS * HIDDEN);
    float* gcnt     = (float*)(ws + off); off = align256(off + sizeof(float) * N_GRAPHS);

    hipMemsetAsync(deg,      0, sizeof(int) * N_NODES, stream);
    hipMemsetAsync(fill_cnt, 0, sizeof(int) * N_NODES, stream);
    hipMemsetAsync(pooled,   0, sizeof(float) * N_GRAPHS * HIDDEN, stream);

    // CSR build (once; reused by both layers)
    deg_kernel  <<<N_EDGES / 256, 256, 0, stream>>>(dst, deg);
    scan1_kernel<<<SCAN_BLOCKS, 256, 0, stream>>>(deg, partials);
    scan2_kernel<<<1, 256, 0, stream>>>(partials, block_off);
    scan3_kernel<<<SCAN_BLOCKS, 256, 0, stream>>>(deg, block_off, row_ptr, inv_deg);
    fill_kernel <<<N_EDGES / 256, 256, 0, stream>>>(src, dst, row_ptr, fill_cnt, csr_src);

    const int agg_blocks  = (N_NODES * 64) / 256;
    const int gemm_blocks = (N_NODES + BM - 1) / BM;

    // layer 0
    agg_kernel<<<agg_blocks, 256, 0, stream>>>(x, row_ptr, csr_src, inv_deg, agg);
    gemm_ln_kernel<<<gemm_blocks, 256, 0, stream>>>(
        agg, x, x_buf, W_rel, b_rel, W_root, gamma, beta);
    // layer 1
    agg_kernel<<<agg_blocks, 256, 0, stream>>>(x_buf, row_ptr, csr_src, inv_deg, agg);
    gemm_ln_kernel<<<gemm_blocks, 256, 0, stream>>>(
        agg, x_buf, x_buf, W_rel + HIDDEN * HIDDEN, b_rel + HIDDEN,
        W_root + HIDDEN * HIDDEN, gamma + HIDDEN, beta + HIDDEN);

    // pooling + head
    pool_kernel<<<POOL_WAVES / 4, 256, 0, stream>>>(x_buf, batch, pooled);
    cnt_kernel<<<1, 128, 0, stream>>>(batch, gcnt);
    out_kernel<<<(N_GRAPHS * OUT_F + 255) / 256, 256, 0, stream>>>(pooled, gcnt, Wc, bc, out);
}

// Round 4
// 418.483 us; speedup vs baseline: 2.2365x; 1.3178x over previous
//
#include <hip/hip_runtime.h>
#include <hip/hip_bf16.h>

#define N_NODES 50000
#define N_EDGES 800000
#define HIDDEN  128
#define OUT_F   10
#define N_GRAPHS 128
#define EPS 1e-5f

#define SCAN_BLOCKS ((N_NODES + 255) / 256)   // 196

using short8 = __attribute__((ext_vector_type(8))) short;
using f32x4  = __attribute__((ext_vector_type(4))) float;

// ---------------------------------------------------------------------------
// casts
__global__ void cast_x_kernel(const float* __restrict__ x, __hip_bfloat16* __restrict__ xb) {
    int i = blockIdx.x * 256 + threadIdx.x;          // one float2 per thread
    if (i < N_NODES * (HIDDEN / 2)) {
        float2 v = ((const float2*)x)[i];
        __hip_bfloat162 o;
        o.x = __float2bfloat16(v.x);
        o.y = __float2bfloat16(v.y);
        ((__hip_bfloat162*)xb)[i] = o;
    }
}

// Wt[l][n][k]: n in [0,128), k in [0,256): k<128 -> W_rel[l][k][n], else W_root[l][k-128][n]
__global__ void cast_w_kernel(const float* __restrict__ Wrel, const float* __restrict__ Wroot,
                              __hip_bfloat16* __restrict__ Wt) {
    int idx = blockIdx.x * 256 + threadIdx.x;        // 2*128*256 = 65536
    int l = idx >> 15;
    int rem = idx & 32767;
    int n = rem >> 8;
    int k = rem & 255;
    float v = (k < HIDDEN) ? Wrel[l * HIDDEN * HIDDEN + k * HIDDEN + n]
                           : Wroot[l * HIDDEN * HIDDEN + (k - HIDDEN) * HIDDEN + n];
    Wt[idx] = __float2bfloat16(v);
}

// ---------------------------------------------------------------------------
// CSR build
__global__ void deg_kernel(const int* __restrict__ dst, int* __restrict__ deg) {
    int e = blockIdx.x * blockDim.x + threadIdx.x;
    if (e < N_EDGES) atomicAdd(&deg[dst[e]], 1);
}

__global__ void scan1_kernel(const int* __restrict__ deg, int* __restrict__ partials) {
    int i = blockIdx.x * 256 + threadIdx.x;
    int v = (i < N_NODES) ? deg[i] : 0;
    #pragma unroll
    for (int off = 1; off < 64; off <<= 1) v += __shfl_xor(v, off, 64);
    __shared__ int s[4];
    if ((threadIdx.x & 63) == 0) s[threadIdx.x >> 6] = v;
    __syncthreads();
    if (threadIdx.x == 0) partials[blockIdx.x] = s[0] + s[1] + s[2] + s[3];
}

__global__ void scan2_kernel(const int* __restrict__ partials, int* __restrict__ block_off) {
    __shared__ int s[256];
    int tid = threadIdx.x;
    int v = (tid < SCAN_BLOCKS) ? partials[tid] : 0;
    s[tid] = v;
    __syncthreads();
    #pragma unroll
    for (int off = 1; off < 256; off <<= 1) {
        int t = (tid >= off) ? s[tid - off] : 0;
        __syncthreads();
        s[tid] += t;
        __syncthreads();
    }
    if (tid < SCAN_BLOCKS) block_off[tid] = s[tid] - v;
}

__global__ void scan3_kernel(const int* __restrict__ deg, const int* __restrict__ block_off,
                             int* __restrict__ row_ptr, float* __restrict__ inv_deg) {
    int i = blockIdx.x * 256 + threadIdx.x;
    int d = (i < N_NODES) ? deg[i] : 0;
    int lane = threadIdx.x & 63;
    int v = d;
    #pragma unroll
    for (int off = 1; off < 64; off <<= 1) {
        int t = __shfl_up(v, off, 64);
        if (lane >= off) v += t;
    }
    __shared__ int wsum[4];
    if (lane == 63) wsum[threadIdx.x >> 6] = v;
    __syncthreads();
    int w = threadIdx.x >> 6;
    int woff = 0;
    #pragma unroll
    for (int j = 0; j < 4; ++j) if (j < w) woff += wsum[j];
    int excl = block_off[blockIdx.x] + woff + v - d;
    if (i < N_NODES) {
        row_ptr[i] = excl;
        inv_deg[i] = (d > 0) ? (1.0f / (float)d) : 0.0f;
    }
    if (blockIdx.x == 0 && threadIdx.x == 0) row_ptr[N_NODES] = N_EDGES;
}

__global__ void fill_kernel(const int* __restrict__ src, const int* __restrict__ dst,
                            const int* __restrict__ row_ptr, int* __restrict__ fill_cnt,
                            int* __restrict__ csr_src) {
    int e = blockIdx.x * blockDim.x + threadIdx.x;
    if (e < N_EDGES) {
        int d = dst[e];
        int p = row_ptr[d] + atomicAdd(&fill_cnt[d], 1);
        csr_src[p] = src[e];
    }
}

// ---------------------------------------------------------------------------
// mean aggregation, bf16 in / fp32 accumulate / bf16 out. One wave per node,
// lane handles 2 features (one bfloat162 = 4B per lane -> 256B/wave/edge).
__global__ void agg_kernel(const __hip_bfloat16* __restrict__ x, const int* __restrict__ row_ptr,
                           const int* __restrict__ csr_src, const float* __restrict__ inv_deg,
                           __hip_bfloat16* __restrict__ agg) {
    int gid = blockIdx.x * blockDim.x + threadIdx.x;
    int node = gid >> 6;
    int lane = threadIdx.x & 63;
    if (node >= N_NODES) return;
    int beg = row_ptr[node], end = row_ptr[node + 1];
    float ax = 0.f, ay = 0.f;
    const __hip_bfloat162* xf = (const __hip_bfloat162*)x;
    for (int e = beg; e < end; ++e) {
        int s = csr_src[e];
        __hip_bfloat162 v = xf[(size_t)s * 64 + lane];
        ax += __bfloat162float(v.x);
        ay += __bfloat162float(v.y);
    }
    float w = inv_deg[node];
    __hip_bfloat162 o;
    o.x = __float2bfloat16(ax * w);
    o.y = __float2bfloat16(ay * w);
    ((__hip_bfloat162*)agg)[(size_t)node * 64 + lane] = o;
}

// ---------------------------------------------------------------------------
// MFMA GEMM + bias + LayerNorm + ReLU, bf16 in/out, fp32 accum.
// Tile: 64 nodes x 128 cols, K=256 ([agg|x] concat). 256 threads = 4 waves;
// wave w owns cols 32w..32w+31 (2 n-tiles). B (weights) resident in regs.
#define GM 64
__global__ __launch_bounds__(256) void gemm_mfma_ln_kernel(
        const __hip_bfloat16* __restrict__ aggb, const __hip_bfloat16* __restrict__ xb,
        __hip_bfloat16* __restrict__ xout,
        const __hip_bfloat16* __restrict__ Wt,   // [128][256] bf16 (n-major)
        const float* __restrict__ brel, const float* __restrict__ gamma,
        const float* __restrict__ beta) {
    __shared__ __align__(16) short sA[GM * 264];   // 64 rows x 256 k, +8 pad
    __shared__ float red[GM][4][2];                // per-row (sum, sumsq) per wave

    const int tid  = threadIdx.x;
    const int w    = tid >> 6;
    const int lane = tid & 63;
    const int q    = lane >> 4;
    const int l15  = lane & 15;
    const int base = blockIdx.x * GM;

    // B fragments: B[n=l15][k=q*8+j] -> rows of Wt. 2 ntiles x 8 ksteps.
    short8 breg[2][8];
    #pragma unroll
    for (int nt = 0; nt < 2; ++nt) {
        int col = 32 * w + nt * 16 + l15;
        const short* wp = (const short*)Wt + (size_t)col * 256;
        #pragma unroll
        for (int ks = 0; ks < 8; ++ks)
            breg[nt][ks] = *(const short8*)(wp + ks * 32 + q * 8);
    }

    // stage A: 64 rows x 32 chunks (8 bf16 each); k 0-127 = agg, 128-255 = x
    for (int it = 0; it < 8; ++it) {
        int c = it * 256 + tid;
        int row = c >> 5, cc = c & 31;
        int node = base + row;
        short8 v = {0,0,0,0,0,0,0,0};
        if (node < N_NODES) {
            const short* gp = (cc < 16)
                ? (const short*)aggb + (size_t)node * HIDDEN + cc * 8
                : (const short*)xb   + (size_t)node * HIDDEN + (cc - 16) * 8;
            v = *(const short8*)gp;
        }
        *(short8*)&sA[row * 264 + cc * 8] = v;
    }
    __syncthreads();

    f32x4 acc[4][2];
    #pragma unroll
    for (int mt = 0; mt < 4; ++mt)
        #pragma unroll
        for (int nt = 0; nt < 2; ++nt)
            acc[mt][nt] = (f32x4){0.f, 0.f, 0.f, 0.f};

    #pragma unroll
    for (int ks = 0; ks < 8; ++ks) {
        short8 a[4];
        #pragma unroll
        for (int mt = 0; mt < 4; ++mt)
            a[mt] = *(short8*)&sA[(mt * 16 + l15) * 264 + ks * 32 + q * 8];
        #pragma unroll
        for (int mt = 0; mt < 4; ++mt) {
            acc[mt][0] = __builtin_amdgcn_mfma_f32_16x16x32_bf16(a[mt], breg[0][ks], acc[mt][0], 0, 0, 0);
            acc[mt][1] = __builtin_amdgcn_mfma_f32_16x16x32_bf16(a[mt], breg[1][ks], acc[mt][1], 0, 0, 0);
        }
    }

    // bias (per col), then per-row partial sums over this wave's 32 cols
    const int col0 = 32 * w + l15, col1 = col0 + 16;
    const float b0 = brel[col0], b1 = brel[col1];
    #pragma unroll
    for (int mt = 0; mt < 4; ++mt) {
        #pragma unroll
        for (int r = 0; r < 4; ++r) {
            acc[mt][0][r] += b0;
            acc[mt][1][r] += b1;
            float s  = acc[mt][0][r] + acc[mt][1][r];
            float s2 = acc[mt][0][r] * acc[mt][0][r] + acc[mt][1][r] * acc[mt][1][r];
            #pragma unroll
            for (int off = 1; off < 16; off <<= 1) {  // reduce across 16-lane group
                s  += __shfl_xor(s,  off, 64);
                s2 += __shfl_xor(s2, off, 64);
            }
            if (l15 == 0) {
                red[mt * 16 + q * 4 + r][w][0] = s;
                red[mt * 16 + q * 4 + r][w][1] = s2;
            }
        }
    }
    __syncthreads();

    const float g0 = gamma[col0], g1 = gamma[col1];
    const float e0 = beta[col0],  e1 = beta[col1];
    #pragma unroll
    for (int mt = 0; mt < 4; ++mt) {
        #pragma unroll
        for (int r = 0; r < 4; ++r) {
            int row = mt * 16 + q * 4 + r;
            float tot  = red[row][0][0] + red[row][1][0] + red[row][2][0] + red[row][3][0];
            float tot2 = red[row][0][1] + red[row][1][1] + red[row][2][1] + red[row][3][1];
            float mu  = tot * (1.0f / HIDDEN);
            float var = tot2 * (1.0f / HIDDEN) - mu * mu;
            float rs  = rsqrtf(var + EPS);
            int node = base + row;
            if (node < N_NODES) {
                float v0 = fmaxf(g0 * (acc[mt][0][r] - mu) * rs + e0, 0.f);
                float v1 = fmaxf(g1 * (acc[mt][1][r] - mu) * rs + e1, 0.f);
                xout[(size_t)node * HIDDEN + col0] = __float2bfloat16(v0);
                xout[(size_t)node * HIDDEN + col1] = __float2bfloat16(v1);
            }
        }
    }
}

// ---------------------------------------------------------------------------
// segmented mean-pool over SORTED batch (bf16 in, fp32 atomics out)
#define POOL_WAVES 1024
#define POOL_CHUNK ((N_NODES + POOL_WAVES - 1) / POOL_WAVES)  // 49
__global__ void pool_kernel(const __hip_bfloat16* __restrict__ x, const int* __restrict__ batch,
                            float* __restrict__ pooled) {
    int wave = blockIdx.x * (blockDim.x >> 6) + (threadIdx.x >> 6);
    int lane = threadIdx.x & 63;
    int n0 = wave * POOL_CHUNK;
    int n1 = n0 + POOL_CHUNK; if (n1 > N_NODES) n1 = N_NODES;
    if (n0 >= N_NODES) return;
    const __hip_bfloat162* xf = (const __hip_bfloat162*)x;
    int cur_g = batch[n0];
    float sx = 0.f, sy = 0.f;
    for (int n = n0; n < n1; ++n) {
        int g = batch[n];
        if (g != cur_g) {
            atomicAdd(&pooled[cur_g * HIDDEN + lane * 2 + 0], sx);
            atomicAdd(&pooled[cur_g * HIDDEN + lane * 2 + 1], sy);
            sx = 0.f; sy = 0.f; cur_g = g;
        }
        __hip_bfloat162 v = xf[(size_t)n * 64 + lane];
        sx += __bfloat162float(v.x);
        sy += __bfloat162float(v.y);
    }
    atomicAdd(&pooled[cur_g * HIDDEN + lane * 2 + 0], sx);
    atomicAdd(&pooled[cur_g * HIDDEN + lane * 2 + 1], sy);
}

__global__ void cnt_kernel(const int* __restrict__ batch, float* __restrict__ gcnt) {
    int g = threadIdx.x;
    if (g >= N_GRAPHS) return;
    int lo = 0, hi = N_NODES;
    while (lo < hi) { int m = (lo + hi) >> 1; if (batch[m] < g) lo = m + 1; else hi = m; }
    int b0 = lo;
    lo = 0; hi = N_NODES;
    while (lo < hi) { int m = (lo + hi) >> 1; if (batch[m] < g + 1) lo = m + 1; else hi = m; }
    gcnt[g] = (float)(lo - b0);
}

__global__ void out_kernel(const float* __restrict__ pooled, const float* __restrict__ gcnt,
                           const float* __restrict__ Wc, const float* __restrict__ bc,
                           float* __restrict__ out) {
    int idx = blockIdx.x * blockDim.x + threadIdx.x;
    if (idx >= N_GRAPHS * OUT_F) return;
    int g = idx / OUT_F, o = idx % OUT_F;
    float inv = 1.0f / fmaxf(gcnt[g], 1.0f);
    float s = 0.f;
    for (int f = 0; f < HIDDEN; ++f)
        s += pooled[g * HIDDEN + f] * Wc[f * OUT_F + o];
    out[idx] = s * inv + bc[o];
}

// ---------------------------------------------------------------------------
static inline size_t align256(size_t v) { return (v + 255) & ~(size_t)255; }

extern "C" void kernel_launch(void* const* d_in, const int* in_sizes, int n_in,
                              void* d_out, int out_size, void* d_ws, size_t ws_size,
                              hipStream_t stream) {
    const float* x      = (const float*)d_in[0];
    const int*   eidx   = (const int*)d_in[1];
    const int*   batch  = (const int*)d_in[2];
    const float* W_rel  = (const float*)d_in[3];
    const float* b_rel  = (const float*)d_in[4];
    const float* W_root = (const float*)d_in[5];
    const float* gamma  = (const float*)d_in[6];
    const float* beta   = (const float*)d_in[7];
    const float* Wc     = (const float*)d_in[8];
    const float* bc     = (const float*)d_in[9];
    float* out = (float*)d_out;

    const int* src = eidx;
    const int* dst = eidx + N_EDGES;

    char* ws = (char*)d_ws;
    size_t off = 0;
    int*   deg      = (int*)(ws + off);  off = align256(off + sizeof(int) * N_NODES);
    int*   row_ptr  = (int*)(ws + off);  off = align256(off + sizeof(int) * (N_NODES + 1));
    int*   fill_cnt = (int*)(ws + off);  off = align256(off + sizeof(int) * N_NODES);
    int*   csr_src  = (int*)(ws + off);  off = align256(off + sizeof(int) * N_EDGES);
    float* inv_deg  = (float*)(ws + off); off = align256(off + sizeof(float) * N_NODES);
    int*   partials = (int*)(ws + off);  off = align256(off + sizeof(int) * SCAN_BLOCKS);
    int*   block_off= (int*)(ws + off);  off = align256(off + sizeof(int) * SCAN_BLOCKS);
    __hip_bfloat16* x0b = (__hip_bfloat16*)(ws + off); off = align256(off + 2 * (size_t)N_NODES * HIDDEN);
    __hip_bfloat16* x1b = (__hip_bfloat16*)(ws + off); off = align256(off + 2 * (size_t)N_NODES * HIDDEN);
    __hip_bfloat16* aggb= (__hip_bfloat16*)(ws + off); off = align256(off + 2 * (size_t)N_NODES * HIDDEN);
    __hip_bfloat16* Wt  = (__hip_bfloat16*)(ws + off); off = align256(off + 2 * (size_t)2 * HIDDEN * 256);
    float* pooled   = (float*)(ws + off); off = align256(off + sizeof(float) * N_GRAPHS * HIDDEN);
    float* gcnt     = (float*)(ws + off); off = align256(off + sizeof(float) * N_GRAPHS);

    hipMemsetAsync(deg,      0, sizeof(int) * N_NODES, stream);
    hipMemsetAsync(fill_cnt, 0, sizeof(int) * N_NODES, stream);
    hipMemsetAsync(pooled,   0, sizeof(float) * N_GRAPHS * HIDDEN, stream);

    // casts
    cast_x_kernel<<<(N_NODES * (HIDDEN / 2) + 255) / 256, 256, 0, stream>>>(x, x0b);
    cast_w_kernel<<<(2 * HIDDEN * 256) / 256, 256, 0, stream>>>(W_rel, W_root, Wt);

    // CSR build (once; reused by both layers)
    deg_kernel  <<<N_EDGES / 256, 256, 0, stream>>>(dst, deg);
    scan1_kernel<<<SCAN_BLOCKS, 256, 0, stream>>>(deg, partials);
    scan2_kernel<<<1, 256, 0, stream>>>(partials, block_off);
    scan3_kernel<<<SCAN_BLOCKS, 256, 0, stream>>>(deg, block_off, row_ptr, inv_deg);
    fill_kernel <<<N_EDGES / 256, 256, 0, stream>>>(src, dst, row_ptr, fill_cnt, csr_src);

    const int agg_blocks  = (N_NODES * 64) / 256;
    const int gemm_blocks = (N_NODES + GM - 1) / GM;   // 782

    // layer 0
    agg_kernel<<<agg_blocks, 256, 0, stream>>>(x0b, row_ptr, csr_src, inv_deg, aggb);
    gemm_mfma_ln_kernel<<<gemm_blocks, 256, 0, stream>>>(
        aggb, x0b, x1b, Wt, b_rel, gamma, beta);
    // layer 1 (row-local; in-place on x1b is safe)
    agg_kernel<<<agg_blocks, 256, 0, stream>>>(x1b, row_ptr, csr_src, inv_deg, aggb);
    gemm_mfma_ln_kernel<<<gemm_blocks, 256, 0, stream>>>(
        aggb, x1b, x1b, Wt + 2 * HIDDEN * 256 / 2, b_rel + HIDDEN,
        gamma + HIDDEN, beta + HIDDEN);

    // pooling + head
    pool_kernel<<<POOL_WAVES / 4, 256, 0, stream>>>(x1b, batch, pooled);
    cnt_kernel<<<1, 128, 0, stream>>>(batch, gcnt);
    out_kernel<<<(N_GRAPHS * OUT_F + 255) / 256, 256, 0, stream>>>(pooled, gcnt, Wc, bc, out);
}

// Round 5
// 328.882 us; speedup vs baseline: 2.8458x; 1.2724x over previous
//
#include <hip/hip_runtime.h>
#include <hip/hip_bf16.h>

#define N_NODES 50000
#define N_EDGES 800000
#define HIDDEN  128
#define OUT_F   10
#define N_GRAPHS 128
#define EPS 1e-5f

#define SCAN_BLOCKS ((N_NODES + 255) / 256)   // 196

using short8 = __attribute__((ext_vector_type(8))) short;
using f32x4  = __attribute__((ext_vector_type(4))) float;

// ---------------------------------------------------------------------------
// casts
__global__ void cast_x_kernel(const float* __restrict__ x, __hip_bfloat16* __restrict__ xb) {
    int i = blockIdx.x * 256 + threadIdx.x;          // one float2 per thread
    if (i < N_NODES * (HIDDEN / 2)) {
        float2 v = ((const float2*)x)[i];
        __hip_bfloat162 o;
        o.x = __float2bfloat16(v.x);
        o.y = __float2bfloat16(v.y);
        ((__hip_bfloat162*)xb)[i] = o;
    }
}

// Wt[l][n][k]: n in [0,128), k in [0,256): k<128 -> W_rel[l][k][n], else W_root[l][k-128][n]
__global__ void cast_w_kernel(const float* __restrict__ Wrel, const float* __restrict__ Wroot,
                              __hip_bfloat16* __restrict__ Wt) {
    int idx = blockIdx.x * 256 + threadIdx.x;        // 2*128*256 = 65536
    int l = idx >> 15;
    int rem = idx & 32767;
    int n = rem >> 8;
    int k = rem & 255;
    float v = (k < HIDDEN) ? Wrel[l * HIDDEN * HIDDEN + k * HIDDEN + n]
                           : Wroot[l * HIDDEN * HIDDEN + (k - HIDDEN) * HIDDEN + n];
    Wt[idx] = __float2bfloat16(v);
}

// ---------------------------------------------------------------------------
// CSR build
__global__ void deg_kernel(const int* __restrict__ dst, int* __restrict__ deg) {
    int e = blockIdx.x * blockDim.x + threadIdx.x;
    if (e < N_EDGES) atomicAdd(&deg[dst[e]], 1);
}

__global__ void scan1_kernel(const int* __restrict__ deg, int* __restrict__ partials) {
    int i = blockIdx.x * 256 + threadIdx.x;
    int v = (i < N_NODES) ? deg[i] : 0;
    #pragma unroll
    for (int off = 1; off < 64; off <<= 1) v += __shfl_xor(v, off, 64);
    __shared__ int s[4];
    if ((threadIdx.x & 63) == 0) s[threadIdx.x >> 6] = v;
    __syncthreads();
    if (threadIdx.x == 0) partials[blockIdx.x] = s[0] + s[1] + s[2] + s[3];
}

__global__ void scan2_kernel(const int* __restrict__ partials, int* __restrict__ block_off) {
    __shared__ int s[256];
    int tid = threadIdx.x;
    int v = (tid < SCAN_BLOCKS) ? partials[tid] : 0;
    s[tid] = v;
    __syncthreads();
    #pragma unroll
    for (int off = 1; off < 256; off <<= 1) {
        int t = (tid >= off) ? s[tid - off] : 0;
        __syncthreads();
        s[tid] += t;
        __syncthreads();
    }
    if (tid < SCAN_BLOCKS) block_off[tid] = s[tid] - v;
}

__global__ void scan3_kernel(const int* __restrict__ deg, const int* __restrict__ block_off,
                             int* __restrict__ row_ptr, float* __restrict__ inv_deg) {
    int i = blockIdx.x * 256 + threadIdx.x;
    int d = (i < N_NODES) ? deg[i] : 0;
    int lane = threadIdx.x & 63;
    int v = d;
    #pragma unroll
    for (int off = 1; off < 64; off <<= 1) {
        int t = __shfl_up(v, off, 64);
        if (lane >= off) v += t;
    }
    __shared__ int wsum[4];
    if (lane == 63) wsum[threadIdx.x >> 6] = v;
    __syncthreads();
    int w = threadIdx.x >> 6;
    int woff = 0;
    #pragma unroll
    for (int j = 0; j < 4; ++j) if (j < w) woff += wsum[j];
    int excl = block_off[blockIdx.x] + woff + v - d;
    if (i < N_NODES) {
        row_ptr[i] = excl;
        inv_deg[i] = (d > 0) ? (1.0f / (float)d) : 0.0f;
    }
    if (blockIdx.x == 0 && threadIdx.x == 0) row_ptr[N_NODES] = N_EDGES;
}

__global__ void fill_kernel(const int* __restrict__ src, const int* __restrict__ dst,
                            const int* __restrict__ row_ptr, int* __restrict__ fill_cnt,
                            int* __restrict__ csr_src) {
    int e = blockIdx.x * blockDim.x + threadIdx.x;
    if (e < N_EDGES) {
        int d = dst[e];
        int p = row_ptr[d] + atomicAdd(&fill_cnt[d], 1);
        csr_src[p] = src[e];
    }
}

// ---------------------------------------------------------------------------
// mean aggregation, high-MLP version. One wave per node. The wave is split
// 32/32: one 8B/lane dwordx2 gather covers TWO edges (512 B). Edge indices
// are preloaded 64-at-a-time with a coalesced lane load and broadcast via
// shfl. Pairs unrolled x4 with independent accumulators for deep pipelining.
__global__ void agg_kernel(const __hip_bfloat16* __restrict__ x, const int* __restrict__ row_ptr,
                           const int* __restrict__ csr_src, const float* __restrict__ inv_deg,
                           __hip_bfloat16* __restrict__ agg) {
    int gid = blockIdx.x * blockDim.x + threadIdx.x;
    int node = gid >> 6;
    int lane = threadIdx.x & 63;
    if (node >= N_NODES) return;
    const int half = lane >> 5;        // 0: even edges, 1: odd edges
    const int l32  = lane & 31;        // feature chunk: 4 bf16 = 8 B
    const int beg = row_ptr[node], end = row_ptr[node + 1];

    float a[4][4];
    #pragma unroll
    for (int u = 0; u < 4; ++u)
        #pragma unroll
        for (int k = 0; k < 4; ++k) a[u][k] = 0.f;

    for (int c = beg; c < end; c += 64) {
        int ei = c + lane;
        int sidx = (ei < end) ? csr_src[ei] : 0;
        int nedge = end - c; if (nedge > 64) nedge = 64;
        int npair = nedge >> 1;
        int j = 0;
        for (; j + 4 <= npair; j += 4) {
            #pragma unroll
            for (int u = 0; u < 4; ++u) {
                int sj = __shfl(sidx, 2 * (j + u) + half, 64);
                float2 v = ((const float2*)(x + (size_t)sj * HIDDEN))[l32];
                __hip_bfloat162 b0 = *(__hip_bfloat162*)&v.x;
                __hip_bfloat162 b1 = *(__hip_bfloat162*)&v.y;
                a[u][0] += __bfloat162float(b0.x);
                a[u][1] += __bfloat162float(b0.y);
                a[u][2] += __bfloat162float(b1.x);
                a[u][3] += __bfloat162float(b1.y);
            }
        }
        for (; j < npair; ++j) {
            int sj = __shfl(sidx, 2 * j + half, 64);
            float2 v = ((const float2*)(x + (size_t)sj * HIDDEN))[l32];
            __hip_bfloat162 b0 = *(__hip_bfloat162*)&v.x;
            __hip_bfloat162 b1 = *(__hip_bfloat162*)&v.y;
            a[0][0] += __bfloat162float(b0.x);
            a[0][1] += __bfloat162float(b0.y);
            a[0][2] += __bfloat162float(b1.x);
            a[0][3] += __bfloat162float(b1.y);
        }
        if (nedge & 1) {
            int sj = __shfl(sidx, nedge - 1, 64);
            if (half == 0) {
                float2 v = ((const float2*)(x + (size_t)sj * HIDDEN))[l32];
                __hip_bfloat162 b0 = *(__hip_bfloat162*)&v.x;
                __hip_bfloat162 b1 = *(__hip_bfloat162*)&v.y;
                a[0][0] += __bfloat162float(b0.x);
                a[0][1] += __bfloat162float(b0.y);
                a[0][2] += __bfloat162float(b1.x);
                a[0][3] += __bfloat162float(b1.y);
            }
        }
    }

    float s0 = a[0][0] + a[1][0] + a[2][0] + a[3][0];
    float s1 = a[0][1] + a[1][1] + a[2][1] + a[3][1];
    float s2 = a[0][2] + a[1][2] + a[2][2] + a[3][2];
    float s3 = a[0][3] + a[1][3] + a[2][3] + a[3][3];
    // combine even/odd halves (feature layout identical in both halves)
    s0 += __shfl_xor(s0, 32, 64);
    s1 += __shfl_xor(s1, 32, 64);
    s2 += __shfl_xor(s2, 32, 64);
    s3 += __shfl_xor(s3, 32, 64);

    if (half == 0) {
        float w = inv_deg[node];
        __hip_bfloat162 p0, p1;
        p0.x = __float2bfloat16(s0 * w);
        p0.y = __float2bfloat16(s1 * w);
        p1.x = __float2bfloat16(s2 * w);
        p1.y = __float2bfloat16(s3 * w);
        __hip_bfloat162* op = (__hip_bfloat162*)agg + (size_t)node * 64 + l32 * 2;
        op[0] = p0;
        op[1] = p1;
    }
}

// ---------------------------------------------------------------------------
// MFMA GEMM + bias + LayerNorm + ReLU, bf16 in/out, fp32 accum.
#define GM 64
__global__ __launch_bounds__(256) void gemm_mfma_ln_kernel(
        const __hip_bfloat16* __restrict__ aggb, const __hip_bfloat16* __restrict__ xb,
        __hip_bfloat16* __restrict__ xout,
        const __hip_bfloat16* __restrict__ Wt,   // [128][256] bf16 (n-major)
        const float* __restrict__ brel, const float* __restrict__ gamma,
        const float* __restrict__ beta) {
    __shared__ __align__(16) short sA[GM * 264];   // 64 rows x 256 k, +8 pad
    __shared__ float red[GM][4][2];                // per-row (sum, sumsq) per wave

    const int tid  = threadIdx.x;
    const int w    = tid >> 6;
    const int lane = tid & 63;
    const int q    = lane >> 4;
    const int l15  = lane & 15;
    const int base = blockIdx.x * GM;

    short8 breg[2][8];
    #pragma unroll
    for (int nt = 0; nt < 2; ++nt) {
        int col = 32 * w + nt * 16 + l15;
        const short* wp = (const short*)Wt + (size_t)col * 256;
        #pragma unroll
        for (int ks = 0; ks < 8; ++ks)
            breg[nt][ks] = *(const short8*)(wp + ks * 32 + q * 8);
    }

    for (int it = 0; it < 8; ++it) {
        int c = it * 256 + tid;
        int row = c >> 5, cc = c & 31;
        int node = base + row;
        short8 v = {0,0,0,0,0,0,0,0};
        if (node < N_NODES) {
            const short* gp = (cc < 16)
                ? (const short*)aggb + (size_t)node * HIDDEN + cc * 8
                : (const short*)xb   + (size_t)node * HIDDEN + (cc - 16) * 8;
            v = *(const short8*)gp;
        }
        *(short8*)&sA[row * 264 + cc * 8] = v;
    }
    __syncthreads();

    f32x4 acc[4][2];
    #pragma unroll
    for (int mt = 0; mt < 4; ++mt)
        #pragma unroll
        for (int nt = 0; nt < 2; ++nt)
            acc[mt][nt] = (f32x4){0.f, 0.f, 0.f, 0.f};

    #pragma unroll
    for (int ks = 0; ks < 8; ++ks) {
        short8 a[4];
        #pragma unroll
        for (int mt = 0; mt < 4; ++mt)
            a[mt] = *(short8*)&sA[(mt * 16 + l15) * 264 + ks * 32 + q * 8];
        #pragma unroll
        for (int mt = 0; mt < 4; ++mt) {
            acc[mt][0] = __builtin_amdgcn_mfma_f32_16x16x32_bf16(a[mt], breg[0][ks], acc[mt][0], 0, 0, 0);
            acc[mt][1] = __builtin_amdgcn_mfma_f32_16x16x32_bf16(a[mt], breg[1][ks], acc[mt][1], 0, 0, 0);
        }
    }

    const int col0 = 32 * w + l15, col1 = col0 + 16;
    const float b0 = brel[col0], b1 = brel[col1];
    #pragma unroll
    for (int mt = 0; mt < 4; ++mt) {
        #pragma unroll
        for (int r = 0; r < 4; ++r) {
            acc[mt][0][r] += b0;
            acc[mt][1][r] += b1;
            float s  = acc[mt][0][r] + acc[mt][1][r];
            float s2 = acc[mt][0][r] * acc[mt][0][r] + acc[mt][1][r] * acc[mt][1][r];
            #pragma unroll
            for (int off = 1; off < 16; off <<= 1) {
                s  += __shfl_xor(s,  off, 64);
                s2 += __shfl_xor(s2, off, 64);
            }
            if (l15 == 0) {
                red[mt * 16 + q * 4 + r][w][0] = s;
                red[mt * 16 + q * 4 + r][w][1] = s2;
            }
        }
    }
    __syncthreads();

    const float g0 = gamma[col0], g1 = gamma[col1];
    const float e0 = beta[col0],  e1 = beta[col1];
    #pragma unroll
    for (int mt = 0; mt < 4; ++mt) {
        #pragma unroll
        for (int r = 0; r < 4; ++r) {
            int row = mt * 16 + q * 4 + r;
            float tot  = red[row][0][0] + red[row][1][0] + red[row][2][0] + red[row][3][0];
            float tot2 = red[row][0][1] + red[row][1][1] + red[row][2][1] + red[row][3][1];
            float mu  = tot * (1.0f / HIDDEN);
            float var = tot2 * (1.0f / HIDDEN) - mu * mu;
            float rs  = rsqrtf(var + EPS);
            int node = base + row;
            if (node < N_NODES) {
                float v0 = fmaxf(g0 * (acc[mt][0][r] - mu) * rs + e0, 0.f);
                float v1 = fmaxf(g1 * (acc[mt][1][r] - mu) * rs + e1, 0.f);
                xout[(size_t)node * HIDDEN + col0] = __float2bfloat16(v0);
                xout[(size_t)node * HIDDEN + col1] = __float2bfloat16(v1);
            }
        }
    }
}

// ---------------------------------------------------------------------------
// segmented mean-pool over SORTED batch (bf16 in, fp32 atomics out)
#define POOL_WAVES 1024
#define POOL_CHUNK ((N_NODES + POOL_WAVES - 1) / POOL_WAVES)  // 49
__global__ void pool_kernel(const __hip_bfloat16* __restrict__ x, const int* __restrict__ batch,
                            float* __restrict__ pooled) {
    int wave = blockIdx.x * (blockDim.x >> 6) + (threadIdx.x >> 6);
    int lane = threadIdx.x & 63;
    int n0 = wave * POOL_CHUNK;
    int n1 = n0 + POOL_CHUNK; if (n1 > N_NODES) n1 = N_NODES;
    if (n0 >= N_NODES) return;
    const __hip_bfloat162* xf = (const __hip_bfloat162*)x;
    int cur_g = batch[n0];
    float sx = 0.f, sy = 0.f;
    for (int n = n0; n < n1; ++n) {
        int g = batch[n];
        if (g != cur_g) {
            atomicAdd(&pooled[cur_g * HIDDEN + lane * 2 + 0], sx);
            atomicAdd(&pooled[cur_g * HIDDEN + lane * 2 + 1], sy);
            sx = 0.f; sy = 0.f; cur_g = g;
        }
        __hip_bfloat162 v = xf[(size_t)n * 64 + lane];
        sx += __bfloat162float(v.x);
        sy += __bfloat162float(v.y);
    }
    atomicAdd(&pooled[cur_g * HIDDEN + lane * 2 + 0], sx);
    atomicAdd(&pooled[cur_g * HIDDEN + lane * 2 + 1], sy);
}

__global__ void cnt_kernel(const int* __restrict__ batch, float* __restrict__ gcnt) {
    int g = threadIdx.x;
    if (g >= N_GRAPHS) return;
    int lo = 0, hi = N_NODES;
    while (lo < hi) { int m = (lo + hi) >> 1; if (batch[m] < g) lo = m + 1; else hi = m; }
    int b0 = lo;
    lo = 0; hi = N_NODES;
    while (lo < hi) { int m = (lo + hi) >> 1; if (batch[m] < g + 1) lo = m + 1; else hi = m; }
    gcnt[g] = (float)(lo - b0);
}

__global__ void out_kernel(const float* __restrict__ pooled, const float* __restrict__ gcnt,
                           const float* __restrict__ Wc, const float* __restrict__ bc,
                           float* __restrict__ out) {
    int idx = blockIdx.x * blockDim.x + threadIdx.x;
    if (idx >= N_GRAPHS * OUT_F) return;
    int g = idx / OUT_F, o = idx % OUT_F;
    float inv = 1.0f / fmaxf(gcnt[g], 1.0f);
    float s = 0.f;
    for (int f = 0; f < HIDDEN; ++f)
        s += pooled[g * HIDDEN + f] * Wc[f * OUT_F + o];
    out[idx] = s * inv + bc[o];
}

// ---------------------------------------------------------------------------
static inline size_t align256(size_t v) { return (v + 255) & ~(size_t)255; }

extern "C" void kernel_launch(void* const* d_in, const int* in_sizes, int n_in,
                              void* d_out, int out_size, void* d_ws, size_t ws_size,
                              hipStream_t stream) {
    const float* x      = (const float*)d_in[0];
    const int*   eidx   = (const int*)d_in[1];
    const int*   batch  = (const int*)d_in[2];
    const float* W_rel  = (const float*)d_in[3];
    const float* b_rel  = (const float*)d_in[4];
    const float* W_root = (const float*)d_in[5];
    const float* gamma  = (const float*)d_in[6];
    const float* beta   = (const float*)d_in[7];
    const float* Wc     = (const float*)d_in[8];
    const float* bc     = (const float*)d_in[9];
    float* out = (float*)d_out;

    const int* src = eidx;
    const int* dst = eidx + N_EDGES;

    char* ws = (char*)d_ws;
    size_t off = 0;
    int*   deg      = (int*)(ws + off);  off = align256(off + sizeof(int) * N_NODES);
    int*   row_ptr  = (int*)(ws + off);  off = align256(off + sizeof(int) * (N_NODES + 1));
    int*   fill_cnt = (int*)(ws + off);  off = align256(off + sizeof(int) * N_NODES);
    int*   csr_src  = (int*)(ws + off);  off = align256(off + sizeof(int) * N_EDGES);
    float* inv_deg  = (float*)(ws + off); off = align256(off + sizeof(float) * N_NODES);
    int*   partials = (int*)(ws + off);  off = align256(off + sizeof(int) * SCAN_BLOCKS);
    int*   block_off= (int*)(ws + off);  off = align256(off + sizeof(int) * SCAN_BLOCKS);
    __hip_bfloat16* x0b = (__hip_bfloat16*)(ws + off); off = align256(off + 2 * (size_t)N_NODES * HIDDEN);
    __hip_bfloat16* x1b = (__hip_bfloat16*)(ws + off); off = align256(off + 2 * (size_t)N_NODES * HIDDEN);
    __hip_bfloat16* aggb= (__hip_bfloat16*)(ws + off); off = align256(off + 2 * (size_t)N_NODES * HIDDEN);
    __hip_bfloat16* Wt  = (__hip_bfloat16*)(ws + off); off = align256(off + 2 * (size_t)2 * HIDDEN * 256);
    float* pooled   = (float*)(ws + off); off = align256(off + sizeof(float) * N_GRAPHS * HIDDEN);
    float* gcnt     = (float*)(ws + off); off = align256(off + sizeof(float) * N_GRAPHS);

    hipMemsetAsync(deg,      0, sizeof(int) * N_NODES, stream);
    hipMemsetAsync(fill_cnt, 0, sizeof(int) * N_NODES, stream);
    hipMemsetAsync(pooled,   0, sizeof(float) * N_GRAPHS * HIDDEN, stream);

    // casts
    cast_x_kernel<<<(N_NODES * (HIDDEN / 2) + 255) / 256, 256, 0, stream>>>(x, x0b);
    cast_w_kernel<<<(2 * HIDDEN * 256) / 256, 256, 0, stream>>>(W_rel, W_root, Wt);

    // CSR build (once; reused by both layers)
    deg_kernel  <<<N_EDGES / 256, 256, 0, stream>>>(dst, deg);
    scan1_kernel<<<SCAN_BLOCKS, 256, 0, stream>>>(deg, partials);
    scan2_kernel<<<1, 256, 0, stream>>>(partials, block_off);
    scan3_kernel<<<SCAN_BLOCKS, 256, 0, stream>>>(deg, block_off, row_ptr, inv_deg);
    fill_kernel <<<N_EDGES / 256, 256, 0, stream>>>(src, dst, row_ptr, fill_cnt, csr_src);

    const int agg_blocks  = (N_NODES * 64) / 256;
    const int gemm_blocks = (N_NODES + GM - 1) / GM;   // 782

    // layer 0
    agg_kernel<<<agg_blocks, 256, 0, stream>>>(x0b, row_ptr, csr_src, inv_deg, aggb);
    gemm_mfma_ln_kernel<<<gemm_blocks, 256, 0, stream>>>(
        aggb, x0b, x1b, Wt, b_rel, gamma, beta);
    // layer 1 (row-local; in-place on x1b is safe)
    agg_kernel<<<agg_blocks, 256, 0, stream>>>(x1b, row_ptr, csr_src, inv_deg, aggb);
    gemm_mfma_ln_kernel<<<gemm_blocks, 256, 0, stream>>>(
        aggb, x1b, x1b, Wt + 2 * HIDDEN * 256 / 2, b_rel + HIDDEN,
        gamma + HIDDEN, beta + HIDDEN);

    // pooling + head
    pool_kernel<<<POOL_WAVES / 4, 256, 0, stream>>>(x1b, batch, pooled);
    cnt_kernel<<<1, 128, 0, stream>>>(batch, gcnt);
    out_kernel<<<(N_GRAPHS * OUT_F + 255) / 256, 256, 0, stream>>>(pooled, gcnt, Wc, bc, out);
}

// Round 6
// 266.150 us; speedup vs baseline: 3.5165x; 1.2357x over previous
//
#include <hip/hip_runtime.h>
#include <hip/hip_bf16.h>

#define N_NODES 50000
#define N_EDGES 800000
#define HIDDEN  128
#define OUT_F   10
#define N_GRAPHS 128
#define EPS 1e-5f

#define NB   391                    // ceil(50000/128) buckets of 128 nodes
#define BCAP 3072                   // bucket capacity (mean 2048, std ~45)
#define SLICE (N_EDGES / 256)       // 3125 edges per partition block

using short8 = __attribute__((ext_vector_type(8))) short;
using f32x4  = __attribute__((ext_vector_type(4))) float;

// ---------------------------------------------------------------------------
// casts
__global__ void cast_x_kernel(const float* __restrict__ x, __hip_bfloat16* __restrict__ xb) {
    int i = blockIdx.x * 256 + threadIdx.x;          // one float2 per thread
    if (i < N_NODES * (HIDDEN / 2)) {
        float2 v = ((const float2*)x)[i];
        __hip_bfloat162 o;
        o.x = __float2bfloat16(v.x);
        o.y = __float2bfloat16(v.y);
        ((__hip_bfloat162*)xb)[i] = o;
    }
}

// Wt[l][n][k]: n in [0,128), k in [0,256): k<128 -> W_rel[l][k][n], else W_root[l][k-128][n]
__global__ void cast_w_kernel(const float* __restrict__ Wrel, const float* __restrict__ Wroot,
                              __hip_bfloat16* __restrict__ Wt) {
    int idx = blockIdx.x * 256 + threadIdx.x;        // 2*128*256 = 65536
    int l = idx >> 15;
    int rem = idx & 32767;
    int n = rem >> 8;
    int k = rem & 255;
    float v = (k < HIDDEN) ? Wrel[l * HIDDEN * HIDDEN + k * HIDDEN + n]
                           : Wroot[l * HIDDEN * HIDDEN + (k - HIDDEN) * HIDDEN + n];
    Wt[idx] = __float2bfloat16(v);
}

// ---------------------------------------------------------------------------
// CSR build via bucket partition (all scatter confined to LDS).
// Phase 1: partition edges into NB buckets by dst>>7, packed src | (dst&127)<<16.
__global__ __launch_bounds__(256) void part_kernel(
        const int* __restrict__ src, const int* __restrict__ dst,
        int* __restrict__ cursor, int* __restrict__ ebuf) {
    __shared__ int s_pk[SLICE];
    __shared__ unsigned short s_bk[SLICE];
    __shared__ int hist[NB], base[NB];
    const int tid = threadIdx.x;
    const int e0 = blockIdx.x * SLICE;
    for (int i = tid; i < NB; i += 256) hist[i] = 0;
    __syncthreads();
    for (int i = tid; i < SLICE; i += 256) {
        int s = src[e0 + i], d = dst[e0 + i];
        int b = d >> 7;
        s_pk[i] = s | ((d & 127) << 16);
        s_bk[i] = (unsigned short)b;
        atomicAdd(&hist[b], 1);
    }
    __syncthreads();
    for (int i = tid; i < NB; i += 256) {
        int h = hist[i];
        base[i] = h ? atomicAdd(&cursor[i], h) : 0;
        hist[i] = 0;                         // reuse as local cursor
    }
    __syncthreads();
    for (int i = tid; i < SLICE; i += 256) {
        int b = s_bk[i];
        int off = base[b] + atomicAdd(&hist[b], 1);
        if (off < BCAP) ebuf[b * BCAP + off] = s_pk[i];
    }
}

// Phase 2: exclusive scan of the NB bucket counts
__global__ void bscan_kernel(const int* __restrict__ cursor, int* __restrict__ bbase,
                             int* __restrict__ row_ptr) {
    __shared__ int s[512];
    int tid = threadIdx.x;
    int v = (tid < NB) ? cursor[tid] : 0;
    s[tid] = v;
    __syncthreads();
    #pragma unroll
    for (int off = 1; off < 512; off <<= 1) {
        int t = (tid >= off) ? s[tid - off] : 0;
        __syncthreads();
        s[tid] += t;
        __syncthreads();
    }
    if (tid < NB) bbase[tid] = s[tid] - v;
    if (tid == 0) row_ptr[N_NODES] = N_EDGES;
}

// Phase 3: per-bucket local counting sort -> deg/inv_deg/row_ptr + coalesced csr write
__global__ __launch_bounds__(256) void fillb_kernel(
        const int* __restrict__ cursor, const int* __restrict__ bbase,
        const int* __restrict__ ebuf,
        int* __restrict__ row_ptr, float* __restrict__ inv_deg,
        int* __restrict__ csr_src) {
    __shared__ int lcsr[BCAP];
    __shared__ int hist[128], lofs[128];
    __shared__ int wtot[2];
    const int b = blockIdx.x;
    const int tid = threadIdx.x;
    int cnt = cursor[b]; if (cnt > BCAP) cnt = BCAP;
    const int base = bbase[b];
    const int* eb = ebuf + b * BCAP;

    if (tid < 128) hist[tid] = 0;
    __syncthreads();
    for (int i = tid; i < cnt; i += 256) atomicAdd(&hist[eb[i] >> 16], 1);
    __syncthreads();
    // exclusive scan of hist[128] via two wave-scans
    if (tid < 128) {
        int lane = tid & 63;
        int v = hist[tid];
        int inc = v;
        #pragma unroll
        for (int off = 1; off < 64; off <<= 1) {
            int t = __shfl_up(inc, off, 64);
            if (lane >= off) inc += t;
        }
        lofs[tid] = inc - v;
        if (lane == 63) wtot[tid >> 6] = inc;
    }
    __syncthreads();
    if (tid >= 64 && tid < 128) lofs[tid] += wtot[0];
    __syncthreads();
    if (tid < 128) {
        int node = b * 128 + tid;
        if (node < N_NODES) {
            row_ptr[node] = base + lofs[tid];
            int d = hist[tid];
            inv_deg[node] = (d > 0) ? (1.0f / (float)d) : 0.0f;
        }
        hist[tid] = lofs[tid];               // becomes running local cursor
    }
    __syncthreads();
    for (int i = tid; i < cnt; i += 256) {
        int pk = eb[i];
        int p = atomicAdd(&hist[pk >> 16], 1);
        lcsr[p] = pk & 0xFFFF;
    }
    __syncthreads();
    for (int i = tid; i < cnt; i += 256) csr_src[base + i] = lcsr[i];
}

// ---------------------------------------------------------------------------
// mean aggregation (unchanged from R5): wave per node, split 32/32 so one
// 8B/lane dwordx2 gather covers TWO edges; x4 unroll for MLP.
__global__ void agg_kernel(const __hip_bfloat16* __restrict__ x, const int* __restrict__ row_ptr,
                           const int* __restrict__ csr_src, const float* __restrict__ inv_deg,
                           __hip_bfloat16* __restrict__ agg) {
    int gid = blockIdx.x * blockDim.x + threadIdx.x;
    int node = gid >> 6;
    int lane = threadIdx.x & 63;
    if (node >= N_NODES) return;
    const int half = lane >> 5;
    const int l32  = lane & 31;
    const int beg = row_ptr[node], end = row_ptr[node + 1];

    float a[4][4];
    #pragma unroll
    for (int u = 0; u < 4; ++u)
        #pragma unroll
        for (int k = 0; k < 4; ++k) a[u][k] = 0.f;

    for (int c = beg; c < end; c += 64) {
        int ei = c + lane;
        int sidx = (ei < end) ? csr_src[ei] : 0;
        int nedge = end - c; if (nedge > 64) nedge = 64;
        int npair = nedge >> 1;
        int j = 0;
        for (; j + 4 <= npair; j += 4) {
            #pragma unroll
            for (int u = 0; u < 4; ++u) {
                int sj = __shfl(sidx, 2 * (j + u) + half, 64);
                float2 v = ((const float2*)(x + (size_t)sj * HIDDEN))[l32];
                __hip_bfloat162 b0 = *(__hip_bfloat162*)&v.x;
                __hip_bfloat162 b1 = *(__hip_bfloat162*)&v.y;
                a[u][0] += __bfloat162float(b0.x);
                a[u][1] += __bfloat162float(b0.y);
                a[u][2] += __bfloat162float(b1.x);
                a[u][3] += __bfloat162float(b1.y);
            }
        }
        for (; j < npair; ++j) {
            int sj = __shfl(sidx, 2 * j + half, 64);
            float2 v = ((const float2*)(x + (size_t)sj * HIDDEN))[l32];
            __hip_bfloat162 b0 = *(__hip_bfloat162*)&v.x;
            __hip_bfloat162 b1 = *(__hip_bfloat162*)&v.y;
            a[0][0] += __bfloat162float(b0.x);
            a[0][1] += __bfloat162float(b0.y);
            a[0][2] += __bfloat162float(b1.x);
            a[0][3] += __bfloat162float(b1.y);
        }
        if (nedge & 1) {
            int sj = __shfl(sidx, nedge - 1, 64);
            if (half == 0) {
                float2 v = ((const float2*)(x + (size_t)sj * HIDDEN))[l32];
                __hip_bfloat162 b0 = *(__hip_bfloat162*)&v.x;
                __hip_bfloat162 b1 = *(__hip_bfloat162*)&v.y;
                a[0][0] += __bfloat162float(b0.x);
                a[0][1] += __bfloat162float(b0.y);
                a[0][2] += __bfloat162float(b1.x);
                a[0][3] += __bfloat162float(b1.y);
            }
        }
    }

    float s0 = a[0][0] + a[1][0] + a[2][0] + a[3][0];
    float s1 = a[0][1] + a[1][1] + a[2][1] + a[3][1];
    float s2 = a[0][2] + a[1][2] + a[2][2] + a[3][2];
    float s3 = a[0][3] + a[1][3] + a[2][3] + a[3][3];
    s0 += __shfl_xor(s0, 32, 64);
    s1 += __shfl_xor(s1, 32, 64);
    s2 += __shfl_xor(s2, 32, 64);
    s3 += __shfl_xor(s3, 32, 64);

    if (half == 0) {
        float w = inv_deg[node];
        __hip_bfloat162 p0, p1;
        p0.x = __float2bfloat16(s0 * w);
        p0.y = __float2bfloat16(s1 * w);
        p1.x = __float2bfloat16(s2 * w);
        p1.y = __float2bfloat16(s3 * w);
        __hip_bfloat162* op = (__hip_bfloat162*)agg + (size_t)node * 64 + l32 * 2;
        op[0] = p0;
        op[1] = p1;
    }
}

// ---------------------------------------------------------------------------
// MFMA GEMM + bias + LayerNorm + ReLU, bf16 in/out, fp32 accum.
#define GM 64
__global__ __launch_bounds__(256) void gemm_mfma_ln_kernel(
        const __hip_bfloat16* __restrict__ aggb, const __hip_bfloat16* __restrict__ xb,
        __hip_bfloat16* __restrict__ xout,
        const __hip_bfloat16* __restrict__ Wt,   // [128][256] bf16 (n-major)
        const float* __restrict__ brel, const float* __restrict__ gamma,
        const float* __restrict__ beta) {
    __shared__ __align__(16) short sA[GM * 264];   // 64 rows x 256 k, +8 pad
    __shared__ float red[GM][4][2];                // per-row (sum, sumsq) per wave

    const int tid  = threadIdx.x;
    const int w    = tid >> 6;
    const int lane = tid & 63;
    const int q    = lane >> 4;
    const int l15  = lane & 15;
    const int base = blockIdx.x * GM;

    short8 breg[2][8];
    #pragma unroll
    for (int nt = 0; nt < 2; ++nt) {
        int col = 32 * w + nt * 16 + l15;
        const short* wp = (const short*)Wt + (size_t)col * 256;
        #pragma unroll
        for (int ks = 0; ks < 8; ++ks)
            breg[nt][ks] = *(const short8*)(wp + ks * 32 + q * 8);
    }

    for (int it = 0; it < 8; ++it) {
        int c = it * 256 + tid;
        int row = c >> 5, cc = c & 31;
        int node = base + row;
        short8 v = {0,0,0,0,0,0,0,0};
        if (node < N_NODES) {
            const short* gp = (cc < 16)
                ? (const short*)aggb + (size_t)node * HIDDEN + cc * 8
                : (const short*)xb   + (size_t)node * HIDDEN + (cc - 16) * 8;
            v = *(const short8*)gp;
        }
        *(short8*)&sA[row * 264 + cc * 8] = v;
    }
    __syncthreads();

    f32x4 acc[4][2];
    #pragma unroll
    for (int mt = 0; mt < 4; ++mt)
        #pragma unroll
        for (int nt = 0; nt < 2; ++nt)
            acc[mt][nt] = (f32x4){0.f, 0.f, 0.f, 0.f};

    #pragma unroll
    for (int ks = 0; ks < 8; ++ks) {
        short8 a[4];
        #pragma unroll
        for (int mt = 0; mt < 4; ++mt)
            a[mt] = *(short8*)&sA[(mt * 16 + l15) * 264 + ks * 32 + q * 8];
        #pragma unroll
        for (int mt = 0; mt < 4; ++mt) {
            acc[mt][0] = __builtin_amdgcn_mfma_f32_16x16x32_bf16(a[mt], breg[0][ks], acc[mt][0], 0, 0, 0);
            acc[mt][1] = __builtin_amdgcn_mfma_f32_16x16x32_bf16(a[mt], breg[1][ks], acc[mt][1], 0, 0, 0);
        }
    }

    const int col0 = 32 * w + l15, col1 = col0 + 16;
    const float b0 = brel[col0], b1 = brel[col1];
    #pragma unroll
    for (int mt = 0; mt < 4; ++mt) {
        #pragma unroll
        for (int r = 0; r < 4; ++r) {
            acc[mt][0][r] += b0;
            acc[mt][1][r] += b1;
            float s  = acc[mt][0][r] + acc[mt][1][r];
            float s2 = acc[mt][0][r] * acc[mt][0][r] + acc[mt][1][r] * acc[mt][1][r];
            #pragma unroll
            for (int off = 1; off < 16; off <<= 1) {
                s  += __shfl_xor(s,  off, 64);
                s2 += __shfl_xor(s2, off, 64);
            }
            if (l15 == 0) {
                red[mt * 16 + q * 4 + r][w][0] = s;
                red[mt * 16 + q * 4 + r][w][1] = s2;
            }
        }
    }
    __syncthreads();

    const float g0 = gamma[col0], g1 = gamma[col1];
    const float e0 = beta[col0],  e1 = beta[col1];
    #pragma unroll
    for (int mt = 0; mt < 4; ++mt) {
        #pragma unroll
        for (int r = 0; r < 4; ++r) {
            int row = mt * 16 + q * 4 + r;
            float tot  = red[row][0][0] + red[row][1][0] + red[row][2][0] + red[row][3][0];
            float tot2 = red[row][0][1] + red[row][1][1] + red[row][2][1] + red[row][3][1];
            float mu  = tot * (1.0f / HIDDEN);
            float var = tot2 * (1.0f / HIDDEN) - mu * mu;
            float rs  = rsqrtf(var + EPS);
            int node = base + row;
            if (node < N_NODES) {
                float v0 = fmaxf(g0 * (acc[mt][0][r] - mu) * rs + e0, 0.f);
                float v1 = fmaxf(g1 * (acc[mt][1][r] - mu) * rs + e1, 0.f);
                xout[(size_t)node * HIDDEN + col0] = __float2bfloat16(v0);
                xout[(size_t)node * HIDDEN + col1] = __float2bfloat16(v1);
            }
        }
    }
}

// ---------------------------------------------------------------------------
// segmented mean-pool over SORTED batch (bf16 in, fp32 atomics out)
#define POOL_WAVES 1024
#define POOL_CHUNK ((N_NODES + POOL_WAVES - 1) / POOL_WAVES)  // 49
__global__ void pool_kernel(const __hip_bfloat16* __restrict__ x, const int* __restrict__ batch,
                            float* __restrict__ pooled) {
    int wave = blockIdx.x * (blockDim.x >> 6) + (threadIdx.x >> 6);
    int lane = threadIdx.x & 63;
    int n0 = wave * POOL_CHUNK;
    int n1 = n0 + POOL_CHUNK; if (n1 > N_NODES) n1 = N_NODES;
    if (n0 >= N_NODES) return;
    const __hip_bfloat162* xf = (const __hip_bfloat162*)x;
    int cur_g = batch[n0];
    float sx = 0.f, sy = 0.f;
    for (int n = n0; n < n1; ++n) {
        int g = batch[n];
        if (g != cur_g) {
            atomicAdd(&pooled[cur_g * HIDDEN + lane * 2 + 0], sx);
            atomicAdd(&pooled[cur_g * HIDDEN + lane * 2 + 1], sy);
            sx = 0.f; sy = 0.f; cur_g = g;
        }
        __hip_bfloat162 v = xf[(size_t)n * 64 + lane];
        sx += __bfloat162float(v.x);
        sy += __bfloat162float(v.y);
    }
    atomicAdd(&pooled[cur_g * HIDDEN + lane * 2 + 0], sx);
    atomicAdd(&pooled[cur_g * HIDDEN + lane * 2 + 1], sy);
}

__global__ void cnt_kernel(const int* __restrict__ batch, float* __restrict__ gcnt) {
    int g = threadIdx.x;
    if (g >= N_GRAPHS) return;
    int lo = 0, hi = N_NODES;
    while (lo < hi) { int m = (lo + hi) >> 1; if (batch[m] < g) lo = m + 1; else hi = m; }
    int b0 = lo;
    lo = 0; hi = N_NODES;
    while (lo < hi) { int m = (lo + hi) >> 1; if (batch[m] < g + 1) lo = m + 1; else hi = m; }
    gcnt[g] = (float)(lo - b0);
}

__global__ void out_kernel(const float* __restrict__ pooled, const float* __restrict__ gcnt,
                           const float* __restrict__ Wc, const float* __restrict__ bc,
                           float* __restrict__ out) {
    int idx = blockIdx.x * blockDim.x + threadIdx.x;
    if (idx >= N_GRAPHS * OUT_F) return;
    int g = idx / OUT_F, o = idx % OUT_F;
    float inv = 1.0f / fmaxf(gcnt[g], 1.0f);
    float s = 0.f;
    for (int f = 0; f < HIDDEN; ++f)
        s += pooled[g * HIDDEN + f] * Wc[f * OUT_F + o];
    out[idx] = s * inv + bc[o];
}

// ---------------------------------------------------------------------------
static inline size_t align256(size_t v) { return (v + 255) & ~(size_t)255; }

extern "C" void kernel_launch(void* const* d_in, const int* in_sizes, int n_in,
                              void* d_out, int out_size, void* d_ws, size_t ws_size,
                              hipStream_t stream) {
    const float* x      = (const float*)d_in[0];
    const int*   eidx   = (const int*)d_in[1];
    const int*   batch  = (const int*)d_in[2];
    const float* W_rel  = (const float*)d_in[3];
    const float* b_rel  = (const float*)d_in[4];
    const float* W_root = (const float*)d_in[5];
    const float* gamma  = (const float*)d_in[6];
    const float* beta   = (const float*)d_in[7];
    const float* Wc     = (const float*)d_in[8];
    const float* bc     = (const float*)d_in[9];
    float* out = (float*)d_out;

    const int* src = eidx;
    const int* dst = eidx + N_EDGES;

    char* ws = (char*)d_ws;
    size_t off = 0;
    int*   row_ptr  = (int*)(ws + off);  off = align256(off + sizeof(int) * (N_NODES + 1));
    int*   csr_src  = (int*)(ws + off);  off = align256(off + sizeof(int) * N_EDGES);
    float* inv_deg  = (float*)(ws + off); off = align256(off + sizeof(float) * N_NODES);
    int*   cursor   = (int*)(ws + off);  off = align256(off + sizeof(int) * NB);
    int*   bbase    = (int*)(ws + off);  off = align256(off + sizeof(int) * NB);
    int*   ebuf     = (int*)(ws + off);  off = align256(off + sizeof(int) * (size_t)NB * BCAP);
    __hip_bfloat16* x0b = (__hip_bfloat16*)(ws + off); off = align256(off + 2 * (size_t)N_NODES * HIDDEN);
    __hip_bfloat16* x1b = (__hip_bfloat16*)(ws + off); off = align256(off + 2 * (size_t)N_NODES * HIDDEN);
    __hip_bfloat16* aggb= (__hip_bfloat16*)(ws + off); off = align256(off + 2 * (size_t)N_NODES * HIDDEN);
    __hip_bfloat16* Wt  = (__hip_bfloat16*)(ws + off); off = align256(off + 2 * (size_t)2 * HIDDEN * 256);
    float* pooled   = (float*)(ws + off); off = align256(off + sizeof(float) * N_GRAPHS * HIDDEN);
    float* gcnt     = (float*)(ws + off); off = align256(off + sizeof(float) * N_GRAPHS);

    hipMemsetAsync(cursor, 0, sizeof(int) * NB, stream);
    hipMemsetAsync(pooled, 0, sizeof(float) * N_GRAPHS * HIDDEN, stream);

    // casts
    cast_x_kernel<<<(N_NODES * (HIDDEN / 2) + 255) / 256, 256, 0, stream>>>(x, x0b);
    cast_w_kernel<<<(2 * HIDDEN * 256) / 256, 256, 0, stream>>>(W_rel, W_root, Wt);

    // CSR build via bucket partition (once; reused by both layers)
    part_kernel <<<256, 256, 0, stream>>>(src, dst, cursor, ebuf);
    bscan_kernel<<<1, 512, 0, stream>>>(cursor, bbase, row_ptr);
    fillb_kernel<<<NB, 256, 0, stream>>>(cursor, bbase, ebuf, row_ptr, inv_deg, csr_src);

    const int agg_blocks  = (N_NODES * 64) / 256;
    const int gemm_blocks = (N_NODES + GM - 1) / GM;   // 782

    // layer 0
    agg_kernel<<<agg_blocks, 256, 0, stream>>>(x0b, row_ptr, csr_src, inv_deg, aggb);
    gemm_mfma_ln_kernel<<<gemm_blocks, 256, 0, stream>>>(
        aggb, x0b, x1b, Wt, b_rel, gamma, beta);
    // layer 1 (row-local; in-place on x1b is safe)
    agg_kernel<<<agg_blocks, 256, 0, stream>>>(x1b, row_ptr, csr_src, inv_deg, aggb);
    gemm_mfma_ln_kernel<<<gemm_blocks, 256, 0, stream>>>(
        aggb, x1b, x1b, Wt + 2 * HIDDEN * 256 / 2, b_rel + HIDDEN,
        gamma + HIDDEN, beta + HIDDEN);

    // pooling + head
    pool_kernel<<<POOL_WAVES / 4, 256, 0, stream>>>(x1b, batch, pooled);
    cnt_kernel<<<1, 128, 0, stream>>>(batch, gcnt);
    out_kernel<<<(N_GRAPHS * OUT_F + 255) / 256, 256, 0, stream>>>(pooled, gcnt, Wc, bc, out);
}

// Round 7
// 265.403 us; speedup vs baseline: 3.5264x; 1.0028x over previous
//
#include <hip/hip_runtime.h>
#include <hip/hip_bf16.h>

#define N_NODES 50000
#define N_EDGES 800000
#define HIDDEN  128
#define OUT_F   10
#define N_GRAPHS 128
#define EPS 1e-5f

#define NB   391                    // ceil(50000/128) buckets of 128 nodes
#define BCAP 3072                   // bucket capacity (mean 2048, std ~45)
#define SLICE (N_EDGES / 256)       // 3125 edges per partition block

using short8 = __attribute__((ext_vector_type(8))) short;
using f32x4  = __attribute__((ext_vector_type(4))) float;

// ---------------------------------------------------------------------------
// casts
__global__ void cast_x_kernel(const float* __restrict__ x, __hip_bfloat16* __restrict__ xb) {
    int i = blockIdx.x * 256 + threadIdx.x;          // one float2 per thread
    if (i < N_NODES * (HIDDEN / 2)) {
        float2 v = ((const float2*)x)[i];
        __hip_bfloat162 o;
        o.x = __float2bfloat16(v.x);
        o.y = __float2bfloat16(v.y);
        ((__hip_bfloat162*)xb)[i] = o;
    }
}

// Wt[l][n][k]: n in [0,128), k in [0,256): k<128 -> W_rel[l][k][n], else W_root[l][k-128][n]
__global__ void cast_w_kernel(const float* __restrict__ Wrel, const float* __restrict__ Wroot,
                              __hip_bfloat16* __restrict__ Wt) {
    int idx = blockIdx.x * 256 + threadIdx.x;        // 2*128*256 = 65536
    int l = idx >> 15;
    int rem = idx & 32767;
    int n = rem >> 8;
    int k = rem & 255;
    float v = (k < HIDDEN) ? Wrel[l * HIDDEN * HIDDEN + k * HIDDEN + n]
                           : Wroot[l * HIDDEN * HIDDEN + (k - HIDDEN) * HIDDEN + n];
    Wt[idx] = __float2bfloat16(v);
}

// ---------------------------------------------------------------------------
// CSR build via bucket partition (all scatter confined to LDS).
__global__ __launch_bounds__(256) void part_kernel(
        const int* __restrict__ src, const int* __restrict__ dst,
        int* __restrict__ cursor, int* __restrict__ ebuf) {
    __shared__ int s_pk[SLICE];
    __shared__ unsigned short s_bk[SLICE];
    __shared__ int hist[NB], base[NB];
    const int tid = threadIdx.x;
    const int e0 = blockIdx.x * SLICE;
    for (int i = tid; i < NB; i += 256) hist[i] = 0;
    __syncthreads();
    for (int i = tid; i < SLICE; i += 256) {
        int s = src[e0 + i], d = dst[e0 + i];
        int b = d >> 7;
        s_pk[i] = s | ((d & 127) << 16);
        s_bk[i] = (unsigned short)b;
        atomicAdd(&hist[b], 1);
    }
    __syncthreads();
    for (int i = tid; i < NB; i += 256) {
        int h = hist[i];
        base[i] = h ? atomicAdd(&cursor[i], h) : 0;
        hist[i] = 0;                         // reuse as local cursor
    }
    __syncthreads();
    for (int i = tid; i < SLICE; i += 256) {
        int b = s_bk[i];
        int off = base[b] + atomicAdd(&hist[b], 1);
        if (off < BCAP) ebuf[b * BCAP + off] = s_pk[i];
    }
}

__global__ void bscan_kernel(const int* __restrict__ cursor, int* __restrict__ bbase,
                             int* __restrict__ row_ptr) {
    __shared__ int s[512];
    int tid = threadIdx.x;
    int v = (tid < NB) ? cursor[tid] : 0;
    s[tid] = v;
    __syncthreads();
    #pragma unroll
    for (int off = 1; off < 512; off <<= 1) {
        int t = (tid >= off) ? s[tid - off] : 0;
        __syncthreads();
        s[tid] += t;
        __syncthreads();
    }
    if (tid < NB) bbase[tid] = s[tid] - v;
    if (tid == 0) row_ptr[N_NODES] = N_EDGES;
}

__global__ __launch_bounds__(256) void fillb_kernel(
        const int* __restrict__ cursor, const int* __restrict__ bbase,
        const int* __restrict__ ebuf,
        int* __restrict__ row_ptr, float* __restrict__ inv_deg,
        int* __restrict__ csr_src) {
    __shared__ int lcsr[BCAP];
    __shared__ int hist[128], lofs[128];
    __shared__ int wtot[2];
    const int b = blockIdx.x;
    const int tid = threadIdx.x;
    int cnt = cursor[b]; if (cnt > BCAP) cnt = BCAP;
    const int base = bbase[b];
    const int* eb = ebuf + b * BCAP;

    if (tid < 128) hist[tid] = 0;
    __syncthreads();
    for (int i = tid; i < cnt; i += 256) atomicAdd(&hist[eb[i] >> 16], 1);
    __syncthreads();
    if (tid < 128) {
        int lane = tid & 63;
        int v = hist[tid];
        int inc = v;
        #pragma unroll
        for (int off = 1; off < 64; off <<= 1) {
            int t = __shfl_up(inc, off, 64);
            if (lane >= off) inc += t;
        }
        lofs[tid] = inc - v;
        if (lane == 63) wtot[tid >> 6] = inc;
    }
    __syncthreads();
    if (tid >= 64 && tid < 128) lofs[tid] += wtot[0];
    __syncthreads();
    if (tid < 128) {
        int node = b * 128 + tid;
        if (node < N_NODES) {
            row_ptr[node] = base + lofs[tid];
            int d = hist[tid];
            inv_deg[node] = (d > 0) ? (1.0f / (float)d) : 0.0f;
        }
        hist[tid] = lofs[tid];               // becomes running local cursor
    }
    __syncthreads();
    for (int i = tid; i < cnt; i += 256) {
        int pk = eb[i];
        int p = atomicAdd(&hist[pk >> 16], 1);
        lcsr[p] = pk & 0xFFFF;
    }
    __syncthreads();
    for (int i = tid; i < cnt; i += 256) csr_src[base + i] = lcsr[i];
}

// ---------------------------------------------------------------------------
// mean aggregation: wave per node, quarter-wave gathers. One dwordx4 per lane
// over 16-lane groups -> one instruction covers FOUR edges (1 KB). Indices
// preloaded 64-wide and broadcast via shfl; 4 independent accumulator sets.
__global__ void agg_kernel(const __hip_bfloat16* __restrict__ x, const int* __restrict__ row_ptr,
                           const int* __restrict__ csr_src, const float* __restrict__ inv_deg,
                           __hip_bfloat16* __restrict__ agg) {
    int gid = blockIdx.x * blockDim.x + threadIdx.x;
    int node = gid >> 6;
    int lane = threadIdx.x & 63;
    if (node >= N_NODES) return;
    const int q = lane >> 4;           // edge slot within a 4-edge group
    const int f = lane & 15;           // feature chunk: 8 bf16 = 16 B
    const int beg = row_ptr[node], end = row_ptr[node + 1];

    float a[4][8];
    #pragma unroll
    for (int u = 0; u < 4; ++u)
        #pragma unroll
        for (int k = 0; k < 8; ++k) a[u][k] = 0.f;

    for (int c = beg; c < end; c += 64) {
        int ei = c + lane;
        int sidx = (ei < end) ? csr_src[ei] : 0;
        int nedge = end - c; if (nedge > 64) nedge = 64;
        int nfull = nedge & ~15;       // multiple of 16
        int j = 0;
        for (; j < nfull; j += 16) {
            #pragma unroll
            for (int u = 0; u < 4; ++u) {
                int sj = __shfl(sidx, j + u * 4 + q, 64);
                float4 v = ((const float4*)(x + (size_t)sj * HIDDEN))[f];
                const __hip_bfloat162* bp = (const __hip_bfloat162*)&v;
                #pragma unroll
                for (int p = 0; p < 4; ++p) {
                    a[u][2 * p + 0] += __bfloat162float(bp[p].x);
                    a[u][2 * p + 1] += __bfloat162float(bp[p].y);
                }
            }
        }
        // remainder (<16 edges): quarter q takes edges j+q, j+q+4, ...
        for (int r = j + q; r < nedge; r += 4) {
            int sj = __shfl(sidx, r, 64);
            float4 v = ((const float4*)(x + (size_t)sj * HIDDEN))[f];
            const __hip_bfloat162* bp = (const __hip_bfloat162*)&v;
            #pragma unroll
            for (int p = 0; p < 4; ++p) {
                a[0][2 * p + 0] += __bfloat162float(bp[p].x);
                a[0][2 * p + 1] += __bfloat162float(bp[p].y);
            }
        }
    }

    float s[8];
    #pragma unroll
    for (int k = 0; k < 8; ++k) {
        s[k] = a[0][k] + a[1][k] + a[2][k] + a[3][k];
        s[k] += __shfl_xor(s[k], 16, 64);
        s[k] += __shfl_xor(s[k], 32, 64);
    }

    if (q == 0) {
        float w = inv_deg[node];
        union { __hip_bfloat162 h[4]; float4 v; } o;
        #pragma unroll
        for (int p = 0; p < 4; ++p) {
            o.h[p].x = __float2bfloat16(s[2 * p + 0] * w);
            o.h[p].y = __float2bfloat16(s[2 * p + 1] * w);
        }
        ((float4*)(agg + (size_t)node * HIDDEN))[f] = o.v;
    }
}

// ---------------------------------------------------------------------------
// MFMA GEMM + bias + LayerNorm + ReLU, bf16 in/out, fp32 accum.
#define GM 64
__global__ __launch_bounds__(256) void gemm_mfma_ln_kernel(
        const __hip_bfloat16* __restrict__ aggb, const __hip_bfloat16* __restrict__ xb,
        __hip_bfloat16* __restrict__ xout,
        const __hip_bfloat16* __restrict__ Wt,   // [128][256] bf16 (n-major)
        const float* __restrict__ brel, const float* __restrict__ gamma,
        const float* __restrict__ beta) {
    __shared__ __align__(16) short sA[GM * 264];   // 64 rows x 256 k, +8 pad
    __shared__ float red[GM][4][2];                // per-row (sum, sumsq) per wave

    const int tid  = threadIdx.x;
    const int w    = tid >> 6;
    const int lane = tid & 63;
    const int q    = lane >> 4;
    const int l15  = lane & 15;
    const int base = blockIdx.x * GM;

    short8 breg[2][8];
    #pragma unroll
    for (int nt = 0; nt < 2; ++nt) {
        int col = 32 * w + nt * 16 + l15;
        const short* wp = (const short*)Wt + (size_t)col * 256;
        #pragma unroll
        for (int ks = 0; ks < 8; ++ks)
            breg[nt][ks] = *(const short8*)(wp + ks * 32 + q * 8);
    }

    for (int it = 0; it < 8; ++it) {
        int c = it * 256 + tid;
        int row = c >> 5, cc = c & 31;
        int node = base + row;
        short8 v = {0,0,0,0,0,0,0,0};
        if (node < N_NODES) {
            const short* gp = (cc < 16)
                ? (const short*)aggb + (size_t)node * HIDDEN + cc * 8
                : (const short*)xb   + (size_t)node * HIDDEN + (cc - 16) * 8;
            v = *(const short8*)gp;
        }
        *(short8*)&sA[row * 264 + cc * 8] = v;
    }
    __syncthreads();

    f32x4 acc[4][2];
    #pragma unroll
    for (int mt = 0; mt < 4; ++mt)
        #pragma unroll
        for (int nt = 0; nt < 2; ++nt)
            acc[mt][nt] = (f32x4){0.f, 0.f, 0.f, 0.f};

    #pragma unroll
    for (int ks = 0; ks < 8; ++ks) {
        short8 a[4];
        #pragma unroll
        for (int mt = 0; mt < 4; ++mt)
            a[mt] = *(short8*)&sA[(mt * 16 + l15) * 264 + ks * 32 + q * 8];
        #pragma unroll
        for (int mt = 0; mt < 4; ++mt) {
            acc[mt][0] = __builtin_amdgcn_mfma_f32_16x16x32_bf16(a[mt], breg[0][ks], acc[mt][0], 0, 0, 0);
            acc[mt][1] = __builtin_amdgcn_mfma_f32_16x16x32_bf16(a[mt], breg[1][ks], acc[mt][1], 0, 0, 0);
        }
    }

    const int col0 = 32 * w + l15, col1 = col0 + 16;
    const float b0 = brel[col0], b1 = brel[col1];
    #pragma unroll
    for (int mt = 0; mt < 4; ++mt) {
        #pragma unroll
        for (int r = 0; r < 4; ++r) {
            acc[mt][0][r] += b0;
            acc[mt][1][r] += b1;
            float s  = acc[mt][0][r] + acc[mt][1][r];
            float s2 = acc[mt][0][r] * acc[mt][0][r] + acc[mt][1][r] * acc[mt][1][r];
            #pragma unroll
            for (int off = 1; off < 16; off <<= 1) {
                s  += __shfl_xor(s,  off, 64);
                s2 += __shfl_xor(s2, off, 64);
            }
            if (l15 == 0) {
                red[mt * 16 + q * 4 + r][w][0] = s;
                red[mt * 16 + q * 4 + r][w][1] = s2;
            }
        }
    }
    __syncthreads();

    const float g0 = gamma[col0], g1 = gamma[col1];
    const float e0 = beta[col0],  e1 = beta[col1];
    #pragma unroll
    for (int mt = 0; mt < 4; ++mt) {
        #pragma unroll
        for (int r = 0; r < 4; ++r) {
            int row = mt * 16 + q * 4 + r;
            float tot  = red[row][0][0] + red[row][1][0] + red[row][2][0] + red[row][3][0];
            float tot2 = red[row][0][1] + red[row][1][1] + red[row][2][1] + red[row][3][1];
            float mu  = tot * (1.0f / HIDDEN);
            float var = tot2 * (1.0f / HIDDEN) - mu * mu;
            float rs  = rsqrtf(var + EPS);
            int node = base + row;
            if (node < N_NODES) {
                float v0 = fmaxf(g0 * (acc[mt][0][r] - mu) * rs + e0, 0.f);
                float v1 = fmaxf(g1 * (acc[mt][1][r] - mu) * rs + e1, 0.f);
                xout[(size_t)node * HIDDEN + col0] = __float2bfloat16(v0);
                xout[(size_t)node * HIDDEN + col1] = __float2bfloat16(v1);
            }
        }
    }
}

// ---------------------------------------------------------------------------
// segmented mean-pool over SORTED batch (bf16 in, fp32 atomics out)
#define POOL_WAVES 1024
#define POOL_CHUNK ((N_NODES + POOL_WAVES - 1) / POOL_WAVES)  // 49
__global__ void pool_kernel(const __hip_bfloat16* __restrict__ x, const int* __restrict__ batch,
                            float* __restrict__ pooled) {
    int wave = blockIdx.x * (blockDim.x >> 6) + (threadIdx.x >> 6);
    int lane = threadIdx.x & 63;
    int n0 = wave * POOL_CHUNK;
    int n1 = n0 + POOL_CHUNK; if (n1 > N_NODES) n1 = N_NODES;
    if (n0 >= N_NODES) return;
    const __hip_bfloat162* xf = (const __hip_bfloat162*)x;
    int cur_g = batch[n0];
    float sx = 0.f, sy = 0.f;
    for (int n = n0; n < n1; ++n) {
        int g = batch[n];
        if (g != cur_g) {
            atomicAdd(&pooled[cur_g * HIDDEN + lane * 2 + 0], sx);
            atomicAdd(&pooled[cur_g * HIDDEN + lane * 2 + 1], sy);
            sx = 0.f; sy = 0.f; cur_g = g;
        }
        __hip_bfloat162 v = xf[(size_t)n * 64 + lane];
        sx += __bfloat162float(v.x);
        sy += __bfloat162float(v.y);
    }
    atomicAdd(&pooled[cur_g * HIDDEN + lane * 2 + 0], sx);
    atomicAdd(&pooled[cur_g * HIDDEN + lane * 2 + 1], sy);
}

// head (also derives per-graph counts from the sorted batch array)
__global__ void out_kernel(const float* __restrict__ pooled, const int* __restrict__ batch,
                           const float* __restrict__ Wc, const float* __restrict__ bc,
                           float* __restrict__ out) {
    int idx = blockIdx.x * blockDim.x + threadIdx.x;
    if (idx >= N_GRAPHS * OUT_F) return;
    int g = idx / OUT_F, o = idx % OUT_F;
    int lo = 0, hi = N_NODES;
    while (lo < hi) { int m = (lo + hi) >> 1; if (batch[m] < g) lo = m + 1; else hi = m; }
    int b0 = lo;
    lo = 0; hi = N_NODES;
    while (lo < hi) { int m = (lo + hi) >> 1; if (batch[m] < g + 1) lo = m + 1; else hi = m; }
    float cntf = (float)(lo - b0);
    float inv = 1.0f / fmaxf(cntf, 1.0f);
    float s = 0.f;
    for (int f = 0; f < HIDDEN; ++f)
        s += pooled[g * HIDDEN + f] * Wc[f * OUT_F + o];
    out[idx] = s * inv + bc[o];
}

// ---------------------------------------------------------------------------
static inline size_t align256(size_t v) { return (v + 255) & ~(size_t)255; }

extern "C" void kernel_launch(void* const* d_in, const int* in_sizes, int n_in,
                              void* d_out, int out_size, void* d_ws, size_t ws_size,
                              hipStream_t stream) {
    const float* x      = (const float*)d_in[0];
    const int*   eidx   = (const int*)d_in[1];
    const int*   batch  = (const int*)d_in[2];
    const float* W_rel  = (const float*)d_in[3];
    const float* b_rel  = (const float*)d_in[4];
    const float* W_root = (const float*)d_in[5];
    const float* gamma  = (const float*)d_in[6];
    const float* beta   = (const float*)d_in[7];
    const float* Wc     = (const float*)d_in[8];
    const float* bc     = (const float*)d_in[9];
    float* out = (float*)d_out;

    const int* src = eidx;
    const int* dst = eidx + N_EDGES;

    char* ws = (char*)d_ws;
    size_t off = 0;
    int*   row_ptr  = (int*)(ws + off);  off = align256(off + sizeof(int) * (N_NODES + 1));
    int*   csr_src  = (int*)(ws + off);  off = align256(off + sizeof(int) * N_EDGES);
    float* inv_deg  = (float*)(ws + off); off = align256(off + sizeof(float) * N_NODES);
    int*   cursor   = (int*)(ws + off);  off = align256(off + sizeof(int) * NB);
    int*   bbase    = (int*)(ws + off);  off = align256(off + sizeof(int) * NB);
    int*   ebuf     = (int*)(ws + off);  off = align256(off + sizeof(int) * (size_t)NB * BCAP);
    __hip_bfloat16* x0b = (__hip_bfloat16*)(ws + off); off = align256(off + 2 * (size_t)N_NODES * HIDDEN);
    __hip_bfloat16* x1b = (__hip_bfloat16*)(ws + off); off = align256(off + 2 * (size_t)N_NODES * HIDDEN);
    __hip_bfloat16* aggb= (__hip_bfloat16*)(ws + off); off = align256(off + 2 * (size_t)N_NODES * HIDDEN);
    __hip_bfloat16* Wt  = (__hip_bfloat16*)(ws + off); off = align256(off + 2 * (size_t)2 * HIDDEN * 256);
    float* pooled   = (float*)(ws + off); off = align256(off + sizeof(float) * N_GRAPHS * HIDDEN);

    hipMemsetAsync(cursor, 0, sizeof(int) * NB, stream);
    hipMemsetAsync(pooled, 0, sizeof(float) * N_GRAPHS * HIDDEN, stream);

    // casts
    cast_x_kernel<<<(N_NODES * (HIDDEN / 2) + 255) / 256, 256, 0, stream>>>(x, x0b);
    cast_w_kernel<<<(2 * HIDDEN * 256) / 256, 256, 0, stream>>>(W_rel, W_root, Wt);

    // CSR build via bucket partition (once; reused by both layers)
    part_kernel <<<256, 256, 0, stream>>>(src, dst, cursor, ebuf);
    bscan_kernel<<<1, 512, 0, stream>>>(cursor, bbase, row_ptr);
    fillb_kernel<<<NB, 256, 0, stream>>>(cursor, bbase, ebuf, row_ptr, inv_deg, csr_src);

    const int agg_blocks  = (N_NODES * 64) / 256;
    const int gemm_blocks = (N_NODES + GM - 1) / GM;   // 782

    // layer 0
    agg_kernel<<<agg_blocks, 256, 0, stream>>>(x0b, row_ptr, csr_src, inv_deg, aggb);
    gemm_mfma_ln_kernel<<<gemm_blocks, 256, 0, stream>>>(
        aggb, x0b, x1b, Wt, b_rel, gamma, beta);
    // layer 1 (row-local; in-place on x1b is safe)
    agg_kernel<<<agg_blocks, 256, 0, stream>>>(x1b, row_ptr, csr_src, inv_deg, aggb);
    gemm_mfma_ln_kernel<<<gemm_blocks, 256, 0, stream>>>(
        aggb, x1b, x1b, Wt + 2 * HIDDEN * 256 / 2, b_rel + HIDDEN,
        gamma + HIDDEN, beta + HIDDEN);

    // pooling + head
    pool_kernel<<<POOL_WAVES / 4, 256, 0, stream>>>(x1b, batch, pooled);
    out_kernel<<<(N_GRAPHS * OUT_F + 255) / 256, 256, 0, stream>>>(pooled, batch, Wc, bc, out);
}